// Round 2
// baseline (2377.254 us; speedup 1.0000x reference)
//
#include <hip/hip_runtime.h>
#include <cstdint>
#include <cstddef>

#define NPTS 8192
#define MCTR 2048
#define BATCH 4
#define KNB 32

typedef float v2f __attribute__((ext_vector_type(2)));

// ---- u32 wave max via DPP (identity 0, values >= 0), foldable to v_max_u32_dpp.
// row_shr:N pushes data to HIGHER lanes; max accumulates in lane 63. ----
__device__ __forceinline__ unsigned wave_max_u32(unsigned x) {
  unsigned t;
  t = (unsigned)__builtin_amdgcn_update_dpp(0, (int)x, 0x111, 0xf, 0xf, false);
  x = x > t ? x : t;
  t = (unsigned)__builtin_amdgcn_update_dpp(0, (int)x, 0x112, 0xf, 0xf, false);
  x = x > t ? x : t;
  t = (unsigned)__builtin_amdgcn_update_dpp(0, (int)x, 0x114, 0xf, 0xf, false);
  x = x > t ? x : t;
  t = (unsigned)__builtin_amdgcn_update_dpp(0, (int)x, 0x118, 0xf, 0xf, false);
  x = x > t ? x : t;
  t = (unsigned)__builtin_amdgcn_update_dpp(0, (int)x, 0x142, 0xa, 0xf, false);
  x = x > t ? x : t;
  t = (unsigned)__builtin_amdgcn_update_dpp(0, (int)x, 0x143, 0xc, 0xf, false);
  x = x > t ? x : t;
  return (unsigned)__builtin_amdgcn_readlane((int)x, 63);
}

// ---- u32 max over lanes 0..7 (accumulates in lane 7), broadcast ----
__device__ __forceinline__ unsigned oct_max_u32(unsigned x) {
  unsigned t;
  t = (unsigned)__builtin_amdgcn_update_dpp(0, (int)x, 0x114, 0xf, 0xf, false);
  x = x > t ? x : t;
  t = (unsigned)__builtin_amdgcn_update_dpp(0, (int)x, 0x112, 0xf, 0xf, false);
  x = x > t ? x : t;
  t = (unsigned)__builtin_amdgcn_update_dpp(0, (int)x, 0x111, 0xf, 0xf, false);
  x = x > t ? x : t;
  return (unsigned)__builtin_amdgcn_readlane((int)x, 7);
}

// ---------- feature transpose (B,32,N) -> (B,N,32) ----------
__global__ __launch_bounds__(256) void featT_kernel(const float* __restrict__ feats,
                                                    float* __restrict__ featT) {
  const int bn = blockIdx.x;
  const int b = bn >> 8;
  const int n0 = (bn & 255) * 32;
  __shared__ float tile[32][33];
  const int tx = threadIdx.x & 31, ty = threadIdx.x >> 5;
  const float* src = feats + (size_t)b * 32 * NPTS;
#pragma unroll
  for (int s = 0; s < 4; ++s) {
    int f = ty + 8 * s;
    tile[f][tx] = src[(size_t)f * NPTS + n0 + tx];
  }
  __syncthreads();
  float* dst = featT + ((size_t)b * NPTS + n0) * 32;
#pragma unroll
  for (int s = 0; s < 4; ++s) {
    int n = ty + 8 * s;
    dst[n * 32 + tx] = tile[tx][n];
  }
}

// ---------- weight transpose ----------
__global__ __launch_bounds__(256) void prep_kernel(const float* __restrict__ W1,
                                                   const float* __restrict__ W2,
                                                   const float* __restrict__ W3,
                                                   float* __restrict__ Wt) {
  const int t = blockIdx.x * 256 + threadIdx.x;
  if (t < 2240) { int c = t >> 6, o = t & 63;  Wt[t] = W1[o * 35 + c]; }
  if (t < 4096) { int c = t >> 6, o = t & 63;  Wt[2240 + t] = W2[o * 64 + c]; }
  if (t < 8192) { int c = t >> 7, o = t & 127; Wt[6336 + t] = W3[o * 64 + c]; }
}

// ---------- furthest point sampling: balanced distributed update ----------
// x-bucket counting sort into LDS (slot-sorted by x). dd[] lives in LDS
// (stride-20 rows, bank-staggered). Each iteration:
//   1) region [lo,hi) = sorted slots with |x-cx| < sqrt(gd) (+margins):
//      provable superset of points whose dd can change (dd_j <= gd).
//      Distributed grid-stride update over ALL 512 threads (balanced).
//   2) barrier; owners of touched 16-slot rows rescan dd from LDS, refresh
//      cached (cmax, amin); two-phase foldable u32 DPP wave reduce.
//   3) barrier; cross-wave oct reduce with candidate-centroid + region
//      prefetch overlapped; winner broadcast by dynamic readlane.
// All selection keyed on (dist, ORIGINAL idx) => any sort permutation gives
// bit-identical output. Distance math: scalar, contract(off), exact ref order.
__global__ __launch_bounds__(512) void fps_kernel(const float* __restrict__ coords,
                                                  int* __restrict__ cidx,
                                                  float* __restrict__ centers) {
  const int b = blockIdx.x;
  const int tid = threadIdx.x;
  const int wave = tid >> 6, lane = tid & 63;
  __shared__ float xL[NPTS], yL[NPTS], zL[NPTS];          // 96 KiB
  __shared__ __align__(16) float ddL[512 * 20];           // 40 KiB, 80B rows
  __shared__ int h[512];                                  // inclusive scan (persists)
  __shared__ int cur[512];
  __shared__ __align__(16) unsigned long long skey[2][8];
  __shared__ int s_slot0;
  const float* C = coords + (size_t)b * 3 * NPTS;
  // --- histogram (x buckets) ---
  h[tid] = 0;
  __syncthreads();
  int bk[16];
#pragma unroll
  for (int j = 0; j < 16; ++j) {
    const int i = tid + j * 512;
    const float x = C[i];
    int k = (int)(x * 512.0f);
    k = k < 0 ? 0 : (k > 511 ? 511 : k);
    bk[j] = k;
    atomicAdd(&h[k], 1);
  }
  __syncthreads();
  // --- Hillis-Steele inclusive scan over h (h persists for region lookup) ---
  const int cnt = h[tid];
  for (int s = 1; s < 512; s <<= 1) {
    int v = (tid >= s) ? h[tid - s] : 0;
    __syncthreads();
    h[tid] += v;
    __syncthreads();
  }
  cur[tid] = h[tid] - cnt;  // exclusive start of bucket tid
  __syncthreads();
  // --- scatter into LDS (orig idx stashed in ddL as int bits) ---
#pragma unroll
  for (int j = 0; j < 16; ++j) {
    const int i = tid + j * 512;
    const int pos = atomicAdd(&cur[bk[j]], 1);
    xL[pos] = C[i];
    yL[pos] = C[NPTS + i];
    zL[pos] = C[2 * NPTS + i];
    ((int*)ddL)[(pos >> 4) * 20 + (pos & 15)] = i;
  }
  __syncthreads();
  // --- owner reads its orig indices, then inits dd = inf ---
  const int base = tid * 16;
  int og[16];
  {
    const int4* irow = (const int4*)(ddL + tid * 20);
    int4 o0 = irow[0], o1 = irow[1], o2 = irow[2], o3 = irow[3];
    og[0] = o0.x; og[1] = o0.y; og[2] = o0.z; og[3] = o0.w;
    og[4] = o1.x; og[5] = o1.y; og[6] = o1.z; og[7] = o1.w;
    og[8] = o2.x; og[9] = o2.y; og[10] = o2.z; og[11] = o2.w;
    og[12] = o3.x; og[13] = o3.y; og[14] = o3.z; og[15] = o3.w;
  }
#pragma unroll
  for (int j = 0; j < 16; ++j)
    if (og[j] == 0) s_slot0 = base + j;  // exactly one thread writes
  {
    float4 fi;
    fi.x = fi.y = fi.z = fi.w = __builtin_inff();
    float4* frow = (float4*)(ddL + tid * 20);
    frow[0] = fi; frow[1] = fi; frow[2] = fi; frow[3] = fi;
  }
  float cmax = __builtin_inff();
  int amin17 = (og[0] << 4) | 0;
#pragma unroll
  for (int j = 1; j < 16; ++j) amin17 = min(amin17, (og[j] << 4) | j);
  __syncthreads();
  const int slot0 = s_slot0;
  float cx = xL[slot0], cy = yL[slot0], cz = zL[slot0];
  int lo = 0, hi = NPTS;  // first region: everything (gd = inf)
  unsigned long long wkey = 0;
  unsigned long long kreg[4];
  if (tid == 0)  // m=0: initial point, orig 0 (dist bits unused by writeback)
    kreg[0] = ((unsigned long long)8191u << 13) | (unsigned)slot0;
  int buf = 0;
  for (int it = 0; it < MCTR; ++it) {
    // ---- phase 1: balanced distributed update over [lo,hi) ----
    for (int s = lo + tid; s < hi; s += 512) {
#pragma clang fp contract(off)
      const float x = xL[s], y = yL[s], z = zL[s];
      const int da = (s >> 4) * 20 + (s & 15);
      const float od = ddL[da];
      const float dx = x - cx;
      const float dy = y - cy;
      const float dz = z - cz;
      const float d = (dx * dx + dy * dy) + dz * dz;  // exact ref order, no FMA
      ddL[da] = fminf(od, d);
    }
    __syncthreads();
    // ---- phase 2: owner rescan (touched rows only) + wave reduce ----
    const bool touched = (base < hi) && (base + 16 > lo);
    const unsigned long long tmask = __ballot(touched ? 1 : 0);
    if (tmask != 0ull) {
      if (touched) {
        const float4* row = (const float4*)(ddL + tid * 20);
        float4 r0 = row[0], r1 = row[1], r2 = row[2], r3 = row[3];
        const float q0 = r0.x, q1 = r0.y, q2 = r0.z, q3 = r0.w;
        const float q4 = r1.x, q5 = r1.y, q6 = r1.z, q7 = r1.w;
        const float q8 = r2.x, q9 = r2.y, q10 = r2.z, q11 = r2.w;
        const float q12 = r3.x, q13 = r3.y, q14 = r3.z, q15 = r3.w;
        const float a0 = fmaxf(q0, q1), a1 = fmaxf(q2, q3);
        const float a2 = fmaxf(q4, q5), a3 = fmaxf(q6, q7);
        const float a4 = fmaxf(q8, q9), a5 = fmaxf(q10, q11);
        const float a6 = fmaxf(q12, q13), a7 = fmaxf(q14, q15);
        const float b0 = fmaxf(a0, a1), b1 = fmaxf(a2, a3);
        const float b2 = fmaxf(a4, a5), b3 = fmaxf(a6, a7);
        cmax = fmaxf(fmaxf(b0, b1), fmaxf(b2, b3));
        const int I = 0x7fffffff;
        int c0 = min(q0 == cmax ? ((og[0] << 4) | 0) : I,
                     q1 == cmax ? ((og[1] << 4) | 1) : I);
        int c1 = min(q2 == cmax ? ((og[2] << 4) | 2) : I,
                     q3 == cmax ? ((og[3] << 4) | 3) : I);
        int c2 = min(q4 == cmax ? ((og[4] << 4) | 4) : I,
                     q5 == cmax ? ((og[5] << 4) | 5) : I);
        int c3 = min(q6 == cmax ? ((og[6] << 4) | 6) : I,
                     q7 == cmax ? ((og[7] << 4) | 7) : I);
        int c4 = min(q8 == cmax ? ((og[8] << 4) | 8) : I,
                     q9 == cmax ? ((og[9] << 4) | 9) : I);
        int c5 = min(q10 == cmax ? ((og[10] << 4) | 10) : I,
                     q11 == cmax ? ((og[11] << 4) | 11) : I);
        int c6 = min(q12 == cmax ? ((og[12] << 4) | 12) : I,
                     q13 == cmax ? ((og[13] << 4) | 13) : I);
        int c7 = min(q14 == cmax ? ((og[14] << 4) | 14) : I,
                     q15 == cmax ? ((og[15] << 4) | 15) : I);
        amin17 = min(min(min(c0, c1), min(c2, c3)), min(min(c4, c5), min(c6, c7)));
      }
      const unsigned mydist = __float_as_uint(cmax);
      const unsigned mytail =
          ((unsigned)(8191 - (amin17 >> 4)) << 13) | (unsigned)(base + (amin17 & 15));
      const unsigned gwd = wave_max_u32(mydist);                       // phase A
      const unsigned gwt = wave_max_u32(mydist == gwd ? mytail : 0u);  // phase B
      wkey = ((unsigned long long)gwd << 32) | gwt;
    }
    if (lane == 0) skey[buf][wave] = wkey;
    __syncthreads();
    // ---- phase 3: cross-wave select; candidate coords + region prefetched ----
    const unsigned long long kc = skey[buf][lane & 7];
    const unsigned kt_ = (unsigned)kc;
    const unsigned kd_ = (unsigned)(kc >> 32);
    const int cslot = (int)(kt_ & 0x1fffu);
    const float fx = xL[cslot], fy = yL[cslot], fz = zL[cslot];  // latency hides under DPP
    // per-candidate region bounds (superset: 2-ulp sqrt margin + 1 bucket pad)
    const float rr = sqrtf(__uint_as_float(kd_)) * 1.000002f;
    const float flo = (fx - rr) * 512.0f, fhi = (fx + rr) * 512.0f;
    int kbl = (int)fmaxf(fminf(flo, 511.0f), 0.0f) - 1;
    kbl = kbl < 0 ? 0 : kbl;
    int kbh = (int)fmaxf(fminf(fhi, 511.0f), 0.0f) + 1;
    kbh = kbh > 511 ? 511 : kbh;
    const int lol = (kbl == 0) ? 0 : h[kbl - 1];
    const int hil = h[kbh];
    const unsigned gd2 = oct_max_u32(kd_);
    const unsigned gt = oct_max_u32(kd_ == gd2 ? kt_ : 0u);
    const unsigned long long gk = ((unsigned long long)gd2 << 32) | gt;
    if (((it + 1) >> 2) == tid) kreg[(it + 1) & 3] = gk;  // winner for m=it+1
    const unsigned long long wm = __ballot(((lane < 8) && (kc == gk)) ? 1 : 0);
    const int wl = (int)__builtin_ctzll(wm);  // winning wave's lane (0..7)
    cx = __uint_as_float((unsigned)__builtin_amdgcn_readlane(__float_as_int(fx), wl));
    cy = __uint_as_float((unsigned)__builtin_amdgcn_readlane(__float_as_int(fy), wl));
    cz = __uint_as_float((unsigned)__builtin_amdgcn_readlane(__float_as_int(fz), wl));
    lo = __builtin_amdgcn_readlane(lol, wl);
    hi = __builtin_amdgcn_readlane(hil, wl);
    buf ^= 1;
  }
  // coalesced writeback: thread t owns centers m = 4t..4t+3
#pragma unroll
  for (int r = 0; r < 4; ++r) {
    unsigned long long k = kreg[r];
    int orig = 8191 - (int)((k >> 13) & 0x1fff);
    int sl = (int)(k & 0x1fff);
    int m = 4 * tid + r;
    cidx[b * MCTR + m] = orig;
    centers[(size_t)b * 3 * MCTR + m] = xL[sl];
    centers[(size_t)b * 3 * MCTR + MCTR + m] = yL[sl];
    centers[(size_t)b * 3 * MCTR + 2 * MCTR + m] = zL[sl];
  }
}

// ---------- ball query: one wave per center, software-pipelined loads ----------
__global__ __launch_bounds__(256) void ballq_kernel(const float* __restrict__ coords,
                                                    const int* __restrict__ cidx,
                                                    int* __restrict__ nbidx) {
  const int wib = threadIdx.x >> 6;
  const int gw = blockIdx.x * 4 + wib;
  const int lane = threadIdx.x & 63;
  const int b = gw >> 11;
  const float* C = coords + (size_t)b * 3 * NPTS;
  const int ci = cidx[gw];
  const float cx = C[ci], cy = C[NPTS + ci], cz = C[2 * NPTS + ci];
  // python double 0.2*0.2 demoted to f32 == 0x3D23D70A (NOT 0.2f*0.2f!)
  const float R2 = (float)(0.2 * 0.2);
  __shared__ int sbuf[4][32];
  int* buf = sbuf[wib];
  int count = 0;
  float xx = C[lane], yy = C[NPTS + lane], zz = C[2 * NPTS + lane];
  for (int base = 0; base < NPTS && count < 32; base += 64) {
    float nx = 0.f, ny = 0.f, nz = 0.f;
    if (base + 64 < NPTS) {  // prefetch next round while this round resolves
      const int ni = base + 64 + lane;
      nx = C[ni]; ny = C[NPTS + ni]; nz = C[2 * NPTS + ni];
    }
    float dx = __fsub_rn(cx, xx);
    float dy = __fsub_rn(cy, yy);
    float dz = __fsub_rn(cz, zz);
    float d2 = __fadd_rn(__fadd_rn(__fmul_rn(dx, dx), __fmul_rn(dy, dy)), __fmul_rn(dz, dz));
    bool q = d2 < R2;
    unsigned long long mk = __ballot(q ? 1 : 0);
    int pos = count + (int)__popcll(mk & ((1ull << lane) - 1ull));
    if (q && pos < 32) buf[pos] = base + lane;
    count += (int)__popcll(mk);
    xx = nx; yy = ny; zz = nz;
  }
  __syncthreads();
  if (lane < 32) {
    int cnt = count < 32 ? count : 32;
    int first = (count > 0) ? buf[0] : 0;
    int v = (lane < cnt) ? buf[lane] : first;
    nbidx[(size_t)gw * KNB + lane] = v;
  }
}

// ---------- MLP with XOR-swizzled LDS ----------
__device__ __forceinline__ int SW(int ch, int col) {
  return 32 * ch + (col ^ ((((ch) >> 2) & 7) << 2));
}

__device__ __forceinline__ void layerT(const float* __restrict__ X,
                                       const float* __restrict__ W, int ldw, int cin,
                                       float4 bias, int og, int kg, float acc[4][8]) {
  const float bv[4] = {bias.x, bias.y, bias.z, bias.w};
#pragma unroll
  for (int oi = 0; oi < 4; ++oi)
#pragma unroll
    for (int ki = 0; ki < 8; ++ki) acc[oi][ki] = bv[oi];
#pragma unroll 4
  for (int c = 0; c < cin; ++c) {
    const float4 xa = *(const float4*)(X + SW(c, 8 * kg));
    const float4 xb = *(const float4*)(X + SW(c, 8 * kg + 4));
    float4 w = *(const float4*)(W + ldw * c + 4 * og);
    const float wv[4] = {w.x, w.y, w.z, w.w};
    const float xv[8] = {xa.x, xa.y, xa.z, xa.w, xb.x, xb.y, xb.z, xb.w};
#pragma unroll
    for (int oi = 0; oi < 4; ++oi)
#pragma unroll
      for (int ki = 0; ki < 8; ++ki)
        acc[oi][ki] = fmaf(wv[oi], xv[ki], acc[oi][ki]);
  }
}

__device__ __forceinline__ void storeT(float* __restrict__ dst, int og, int kg,
                                       const float acc[4][8]) {
#pragma unroll
  for (int oi = 0; oi < 4; ++oi) {
    float4 va, vb;
    va.x = fmaxf(acc[oi][0], 0.f); va.y = fmaxf(acc[oi][1], 0.f);
    va.z = fmaxf(acc[oi][2], 0.f); va.w = fmaxf(acc[oi][3], 0.f);
    vb.x = fmaxf(acc[oi][4], 0.f); vb.y = fmaxf(acc[oi][5], 0.f);
    vb.z = fmaxf(acc[oi][6], 0.f); vb.w = fmaxf(acc[oi][7], 0.f);
    const int r = 4 * og + oi;
    *(float4*)(dst + SW(r, 8 * kg)) = va;
    *(float4*)(dst + SW(r, 8 * kg + 4)) = vb;
  }
}

__global__ __launch_bounds__(64) void mlp_kernel(const float* __restrict__ coords,
                                                 const float* __restrict__ featT,
                                                 const float* __restrict__ Wt,
                                                 const float* __restrict__ b1,
                                                 const float* __restrict__ b2,
                                                 const float* __restrict__ b3,
                                                 const int* __restrict__ cidx,
                                                 const int* __restrict__ nbidx,
                                                 float* __restrict__ outT) {
  const int g = blockIdx.x;
  const int b = g >> 11;
  const int lane = threadIdx.x;
  const int og = lane & 15, kg = lane >> 4;
  __shared__ __align__(16) float A[64 * 32];
  __shared__ __align__(16) float Bf[64 * 32];
  const float* C = coords + (size_t)b * 3 * NPTS;
  const int ci = cidx[g];
  const float ccx = C[ci], ccy = C[NPTS + ci], ccz = C[2 * NPTS + ci];
  const int* nb = nbidx + (size_t)g * KNB;
  if (lane < 32) {
    const int n = nb[lane];
    A[SW(0, lane)] = C[n] - ccx;
    A[SW(1, lane)] = C[NPTS + n] - ccy;
    A[SW(2, lane)] = C[2 * NPTS + n] - ccz;
    const float4* f = (const float4*)(featT + ((size_t)b * NPTS + n) * 32);
#pragma unroll
    for (int q = 0; q < 4; ++q) {
      float4 v = f[q];
      A[SW(3 + 4 * q, lane)] = v.x;
      A[SW(4 + 4 * q, lane)] = v.y;
      A[SW(5 + 4 * q, lane)] = v.z;
      A[SW(6 + 4 * q, lane)] = v.w;
    }
  } else {
    const int k = lane - 32;
    const int n = nb[k];
    const float4* f = (const float4*)(featT + ((size_t)b * NPTS + n) * 32);
#pragma unroll
    for (int q = 4; q < 8; ++q) {
      float4 v = f[q];
      A[SW(3 + 4 * q, k)] = v.x;
      A[SW(4 + 4 * q, k)] = v.y;
      A[SW(5 + 4 * q, k)] = v.z;
      A[SW(6 + 4 * q, k)] = v.w;
    }
  }
  __syncthreads();
  float acc[4][8];
  layerT(A, Wt, 64, 35, *(const float4*)(b1 + 4 * og), og, kg, acc);
  storeT(Bf, og, kg, acc);
  __syncthreads();
  layerT(Bf, Wt + 2240, 64, 64, *(const float4*)(b2 + 4 * og), og, kg, acc);
  storeT(A, og, kg, acc);
  __syncthreads();
  float* outp = outT + (size_t)g * 128;
#pragma unroll 1
  for (int h = 0; h < 2; ++h) {
    layerT(A, Wt + 6336 + 64 * h, 128, 64, *(const float4*)(b3 + 64 * h + 4 * og), og,
           kg, acc);
    float4 res;
    float* rp = (float*)&res;
#pragma unroll
    for (int oi = 0; oi < 4; ++oi) {
      float m = 0.f;
#pragma unroll
      for (int ki = 0; ki < 8; ++ki) m = fmaxf(m, acc[oi][ki]);
      m = fmaxf(m, __shfl_xor(m, 16));
      m = fmaxf(m, __shfl_xor(m, 32));
      rp[oi] = m;
    }
    if (kg == 0) *(float4*)(outp + 64 * h + 4 * og) = res;
  }
}

// ---------- output transpose (B,M,128) -> (B,128,M) ----------
__global__ __launch_bounds__(256) void outT_kernel(const float* __restrict__ outT,
                                                   float* __restrict__ out) {
  const int bid = blockIdx.x;
  const int b = bid >> 8;
  const int r = bid & 255;
  const int o0 = (r >> 6) * 32;
  const int m0 = (r & 63) * 32;
  __shared__ float tile[32][33];
  const int tx = threadIdx.x & 31, ty = threadIdx.x >> 5;
  const float* src = outT + ((size_t)b * MCTR + m0) * 128;
#pragma unroll
  for (int s = 0; s < 4; ++s) {
    int m = ty + 8 * s;
    tile[m][tx] = src[(size_t)m * 128 + o0 + tx];
  }
  __syncthreads();
  float* dst = out + ((size_t)b * 128 + o0) * MCTR + m0;
#pragma unroll
  for (int s = 0; s < 4; ++s) {
    int o = ty + 8 * s;
    dst[(size_t)o * MCTR + tx] = tile[tx][o];
  }
}

extern "C" void kernel_launch(void* const* d_in, const int* in_sizes, int n_in,
                              void* d_out, int out_size, void* d_ws, size_t ws_size,
                              hipStream_t stream) {
  (void)in_sizes; (void)n_in; (void)out_size; (void)ws_size;
  const float* feats = (const float*)d_in[0];
  const float* coords = (const float*)d_in[1];
  const float* W1 = (const float*)d_in[2];
  const float* b1 = (const float*)d_in[3];
  const float* W2 = (const float*)d_in[4];
  const float* b2 = (const float*)d_in[5];
  const float* W3 = (const float*)d_in[6];
  const float* b3 = (const float*)d_in[7];
  float* out = (float*)d_out;
  float* centers = out + (size_t)BATCH * 128 * MCTR;

  float* ws_f = (float*)d_ws;
  float* featT = ws_f;                                     // 1,048,576 f
  float* Wt = ws_f + 1048576;                              //    14,528 f
  int* cidx = (int*)(ws_f + 1048576 + 14528);              //     8,192 i
  int* nbidx = (int*)(ws_f + 1048576 + 14528 + 8192);      //   262,144 i
  float* outTbuf = ws_f + 1048576 + 14528 + 8192 + 262144; // 1,048,576 f

  featT_kernel<<<1024, 256, 0, stream>>>(feats, featT);
  prep_kernel<<<32, 256, 0, stream>>>(W1, W2, W3, Wt);
  fps_kernel<<<BATCH, 512, 0, stream>>>(coords, cidx, centers);
  ballq_kernel<<<2048, 256, 0, stream>>>(coords, cidx, nbidx);
  mlp_kernel<<<BATCH * MCTR, 64, 0, stream>>>(coords, featT, Wt, b1, b2, b3, cidx, nbidx, outTbuf);
  outT_kernel<<<1024, 256, 0, stream>>>(outTbuf, out);
}

// Round 3
// 1884.824 us; speedup vs baseline: 1.2613x; 1.2613x over previous
//
#include <hip/hip_runtime.h>
#include <cstdint>
#include <cstddef>

#define NPTS 8192
#define MCTR 2048
#define BATCH 4
#define KNB 32

typedef float v2f __attribute__((ext_vector_type(2)));

// ---- u32 wave max via DPP (identity 0, values >= 0), foldable to v_max_u32_dpp.
// row_shr:N pushes data to HIGHER lanes; max accumulates in lane 63. ----
__device__ __forceinline__ unsigned wave_max_u32(unsigned x) {
  unsigned t;
  t = (unsigned)__builtin_amdgcn_update_dpp(0, (int)x, 0x111, 0xf, 0xf, false);
  x = x > t ? x : t;
  t = (unsigned)__builtin_amdgcn_update_dpp(0, (int)x, 0x112, 0xf, 0xf, false);
  x = x > t ? x : t;
  t = (unsigned)__builtin_amdgcn_update_dpp(0, (int)x, 0x114, 0xf, 0xf, false);
  x = x > t ? x : t;
  t = (unsigned)__builtin_amdgcn_update_dpp(0, (int)x, 0x118, 0xf, 0xf, false);
  x = x > t ? x : t;
  t = (unsigned)__builtin_amdgcn_update_dpp(0, (int)x, 0x142, 0xa, 0xf, false);
  x = x > t ? x : t;
  t = (unsigned)__builtin_amdgcn_update_dpp(0, (int)x, 0x143, 0xc, 0xf, false);
  x = x > t ? x : t;
  return (unsigned)__builtin_amdgcn_readlane((int)x, 63);
}

// ---- u32 max over lanes 0..7 (accumulates in lane 7), broadcast ----
__device__ __forceinline__ unsigned oct_max_u32(unsigned x) {
  unsigned t;
  t = (unsigned)__builtin_amdgcn_update_dpp(0, (int)x, 0x114, 0xf, 0xf, false);
  x = x > t ? x : t;
  t = (unsigned)__builtin_amdgcn_update_dpp(0, (int)x, 0x112, 0xf, 0xf, false);
  x = x > t ? x : t;
  t = (unsigned)__builtin_amdgcn_update_dpp(0, (int)x, 0x111, 0xf, 0xf, false);
  x = x > t ? x : t;
  return (unsigned)__builtin_amdgcn_readlane((int)x, 7);
}

// ---------- feature transpose (B,32,N) -> (B,N,32) ----------
__global__ __launch_bounds__(256) void featT_kernel(const float* __restrict__ feats,
                                                    float* __restrict__ featT) {
  const int bn = blockIdx.x;
  const int b = bn >> 8;
  const int n0 = (bn & 255) * 32;
  __shared__ float tile[32][33];
  const int tx = threadIdx.x & 31, ty = threadIdx.x >> 5;
  const float* src = feats + (size_t)b * 32 * NPTS;
#pragma unroll
  for (int s = 0; s < 4; ++s) {
    int f = ty + 8 * s;
    tile[f][tx] = src[(size_t)f * NPTS + n0 + tx];
  }
  __syncthreads();
  float* dst = featT + ((size_t)b * NPTS + n0) * 32;
#pragma unroll
  for (int s = 0; s < 4; ++s) {
    int n = ty + 8 * s;
    dst[n * 32 + tx] = tile[tx][n];
  }
}

// ---------- weight transpose ----------
__global__ __launch_bounds__(256) void prep_kernel(const float* __restrict__ W1,
                                                   const float* __restrict__ W2,
                                                   const float* __restrict__ W3,
                                                   float* __restrict__ Wt) {
  const int t = blockIdx.x * 256 + threadIdx.x;
  if (t < 2240) { int c = t >> 6, o = t & 63;  Wt[t] = W1[o * 35 + c]; }
  if (t < 4096) { int c = t >> 6, o = t & 63;  Wt[2240 + t] = W2[o * 64 + c]; }
  if (t < 8192) { int c = t >> 7, o = t & 127; Wt[6336 + t] = W3[o * 64 + c]; }
}

// ---------- furthest point sampling (with fused in-LDS counting sort) ----------
// PROVEN R12/x-sort structure (1520us): counting sort by x-bucket into LDS
// lC4[] (orig idx bit-stashed in .w), blocked ownership (thread t owns slots
// [16t,16t+16)), exact bbox cull, packed register-resident hot loop (fp
// contract off == bit-exact vs reference), one barrier per iteration.
// ROUND-3 surgical tail cuts (update loop untouched):
//  (a) phase-B wave reduce (tail among dist-achievers) via ballot +
//      wave-uniform readlane loop (typ. 1 lane) instead of a second 6-step
//      DPP chain (~150cy -> ~30cy);
//  (b) same for the cross-wave oct phase-B (8-lane mask);
//  (c) candidate centroid float4 prefetched by ALL lanes right after the
//      skey read (latency overlaps oct DPP chain); winner xyz broadcast by
//      3 dynamic readlanes instead of a dependent ds_read_b128 (~120cy).
// Selection still keyed exactly on (max dist, min ORIGINAL idx) == jnp.argmax
// first occurrence; sort is only a permutation => bit-identical output.
__global__ __launch_bounds__(512) void fps_kernel(const float* __restrict__ coords,
                                                  int* __restrict__ cidx,
                                                  float* __restrict__ centers) {
  const int b = blockIdx.x;
  const int tid = threadIdx.x;
  const int wave = tid >> 6, lane = tid & 63;
  __shared__ __align__(16) float4 lC4[NPTS];  // 128 KiB (w = orig idx bits)
  __shared__ __align__(16) unsigned long long skey[2][8];
  __shared__ int h[512];
  __shared__ int cur[512];
  __shared__ int s_slot0;
  const float* C = coords + (size_t)b * 3 * NPTS;
  // --- histogram ---
  h[tid] = 0;
  __syncthreads();
  int bk[16];
#pragma unroll
  for (int j = 0; j < 16; ++j) {
    const int i = tid + j * 512;
    const float x = C[i];
    int k = (int)(x * 512.0f);
    k = k < 0 ? 0 : (k > 511 ? 511 : k);
    bk[j] = k;
    atomicAdd(&h[k], 1);
  }
  __syncthreads();
  // --- Hillis-Steele inclusive scan over h ---
  const int cnt = h[tid];
  for (int s = 1; s < 512; s <<= 1) {
    int v = (tid >= s) ? h[tid - s] : 0;
    __syncthreads();
    h[tid] += v;
    __syncthreads();
  }
  cur[tid] = h[tid] - cnt;  // exclusive start of bucket tid
  __syncthreads();
  // --- scatter into LDS (within-bucket order nondeterministic; harmless) ---
#pragma unroll
  for (int j = 0; j < 16; ++j) {
    const int i = tid + j * 512;
    const int pos = atomicAdd(&cur[bk[j]], 1);
    float4 v;
    v.x = C[i];
    v.y = C[NPTS + i];
    v.z = C[2 * NPTS + i];
    v.w = __int_as_float(i);  // ORIGINAL index, bit-stashed
    lC4[pos] = v;
  }
  __syncthreads();
  // --- blocked read of owned slots ---
  const int base = tid * 16;
  int og[16];
  v2f px[8], py[8], pz[8], dd[8];
#pragma unroll
  for (int p = 0; p < 8; ++p) {
    float4 c0 = lC4[base + 2 * p];
    float4 c1 = lC4[base + 2 * p + 1];
    px[p].x = c0.x; px[p].y = c1.x;
    py[p].x = c0.y; py[p].y = c1.y;
    pz[p].x = c0.z; pz[p].y = c1.z;
    og[2 * p] = __float_as_int(c0.w);
    og[2 * p + 1] = __float_as_int(c1.w);
    dd[p].x = __builtin_inff(); dd[p].y = __builtin_inff();
  }
#pragma unroll
  for (int j = 0; j < 16; ++j)
    if (og[j] == 0) s_slot0 = base + j;  // exactly one thread writes
  // exact bbox of owned points
  v2f xl = px[0], xh = px[0], yl = py[0], yh = py[0], zl = pz[0], zh = pz[0];
#pragma unroll
  for (int p = 1; p < 8; ++p) {
    xl = __builtin_elementwise_min(xl, px[p]); xh = __builtin_elementwise_max(xh, px[p]);
    yl = __builtin_elementwise_min(yl, py[p]); yh = __builtin_elementwise_max(yh, py[p]);
    zl = __builtin_elementwise_min(zl, pz[p]); zh = __builtin_elementwise_max(zh, pz[p]);
  }
  const float xlo = fminf(xl.x, xl.y), xhi = fmaxf(xh.x, xh.y);
  const float ylo = fminf(yl.x, yl.y), yhi = fmaxf(yh.x, yh.y);
  const float zlo = fminf(zl.x, zl.y), zhi = fmaxf(zh.x, zh.y);
  __syncthreads();
  float cmax = __builtin_inff();
  int amin17 = (og[0] << 4) | 0;
#pragma unroll
  for (int j = 1; j < 16; ++j) amin17 = min(amin17, (og[j] << 4) | j);
  const int slot0 = s_slot0;
  float4 cc = lC4[slot0];
  float cx = cc.x, cy = cc.y, cz = cc.z;
  unsigned long long wkey = 0;
  unsigned long long kreg[4];
  if (tid == 0)  // m=0: initial point, orig 0 (dist bits unused by writeback)
    kreg[0] = ((unsigned long long)(unsigned)8191 << 13) | (unsigned)slot0;
  int buf = 0;
  for (int it = 0; it < MCTR; ++it) {
    float dxm = fmaxf(fmaxf(xlo - cx, cx - xhi), 0.0f);
    float dym = fmaxf(fmaxf(ylo - cy, cy - yhi), 0.0f);
    float dzm = fmaxf(fmaxf(zlo - cz, cz - zhi), 0.0f);
    float lb = dxm * dxm + dym * dym + dzm * dzm;
    bool active = !(lb * 0.999999f >= cmax);  // margin makes skip provably exact
    unsigned long long mk = __ballot(active ? 1 : 0);
    if (mk != 0ull) {
      if (active) {
        v2f vcx, vcy, vcz;
        vcx.x = cx; vcx.y = cx;
        vcy.x = cy; vcy.y = cy;
        vcz.x = cz; vcz.y = cz;
        {
#pragma clang fp contract(off)
          // EXACT reference order per half: (dx*dx + dy*dy) + dz*dz, rn each
          // step, no FMA (contract off). Packed == scalar bit-exact.
#pragma unroll
          for (int p = 0; p < 8; ++p) {
            v2f dx = px[p] - vcx;
            v2f dy = py[p] - vcy;
            v2f dz = pz[p] - vcz;
            v2f d = (dx * dx + dy * dy) + dz * dz;
            dd[p] = __builtin_elementwise_min(dd[p], d);
          }
        }
        v2f m01 = __builtin_elementwise_max(dd[0], dd[1]);
        v2f m23 = __builtin_elementwise_max(dd[2], dd[3]);
        v2f m45 = __builtin_elementwise_max(dd[4], dd[5]);
        v2f m67 = __builtin_elementwise_max(dd[6], dd[7]);
        v2f m03 = __builtin_elementwise_max(m01, m23);
        v2f m47 = __builtin_elementwise_max(m45, m67);
        v2f mm = __builtin_elementwise_max(m03, m47);
        cmax = fmaxf(mm.x, mm.y);
        // min ORIGINAL idx among achievers — depth-4 tree
        int c0, c1, c2, c3, c4, c5, c6, c7;
        c0 = min(dd[0].x == cmax ? ((og[0] << 4) | 0) : 0x7fffffff,
                 dd[0].y == cmax ? ((og[1] << 4) | 1) : 0x7fffffff);
        c1 = min(dd[1].x == cmax ? ((og[2] << 4) | 2) : 0x7fffffff,
                 dd[1].y == cmax ? ((og[3] << 4) | 3) : 0x7fffffff);
        c2 = min(dd[2].x == cmax ? ((og[4] << 4) | 4) : 0x7fffffff,
                 dd[2].y == cmax ? ((og[5] << 4) | 5) : 0x7fffffff);
        c3 = min(dd[3].x == cmax ? ((og[6] << 4) | 6) : 0x7fffffff,
                 dd[3].y == cmax ? ((og[7] << 4) | 7) : 0x7fffffff);
        c4 = min(dd[4].x == cmax ? ((og[8] << 4) | 8) : 0x7fffffff,
                 dd[4].y == cmax ? ((og[9] << 4) | 9) : 0x7fffffff);
        c5 = min(dd[5].x == cmax ? ((og[10] << 4) | 10) : 0x7fffffff,
                 dd[5].y == cmax ? ((og[11] << 4) | 11) : 0x7fffffff);
        c6 = min(dd[6].x == cmax ? ((og[12] << 4) | 12) : 0x7fffffff,
                 dd[6].y == cmax ? ((og[13] << 4) | 13) : 0x7fffffff);
        c7 = min(dd[7].x == cmax ? ((og[14] << 4) | 14) : 0x7fffffff,
                 dd[7].y == cmax ? ((og[15] << 4) | 15) : 0x7fffffff);
        amin17 = min(min(min(c0, c1), min(c2, c3)), min(min(c4, c5), min(c6, c7)));
      }
      const unsigned mydist = __float_as_uint(cmax);
      const unsigned mytail =
          ((unsigned)(8191 - (amin17 >> 4)) << 13) | (unsigned)(base + (amin17 & 15));
      const unsigned gwd = wave_max_u32(mydist);  // phase A (6-step DPP)
      // phase B: max tail among dist-achievers — ballot + wave-uniform
      // readlane loop (typ. exactly 1 lane; tails unique per slot).
      unsigned long long am = __ballot(mydist == gwd ? 1 : 0);
      unsigned gwt = 0;
      while (am) {
        const int l = (int)__builtin_ctzll(am);
        am &= am - 1;
        const unsigned v = (unsigned)__builtin_amdgcn_readlane((int)mytail, l);
        gwt = gwt > v ? gwt : v;
      }
      wkey = ((unsigned long long)gwd << 32) | gwt;
    }
    if (lane == 0) skey[buf][wave] = wkey;
    __syncthreads();
    // ---- cross-wave select: prefetch candidates, oct-A DPP, masked loop B ----
    const unsigned long long kc = skey[buf][lane & 7];
    const unsigned kd = (unsigned)(kc >> 32), kt = (unsigned)kc;
    const int cslot = (int)(kt & 0x1fffu);
    const float4 cand = lC4[cslot];  // prefetch; latency hides under oct DPP
    const unsigned gd = oct_max_u32(kd);
    unsigned long long am8 = __ballot((lane < 8) && (kd == gd) ? 1 : 0) & 0xffull;
    unsigned gt = 0;
    while (am8) {
      const int l = (int)__builtin_ctzll(am8);
      am8 &= am8 - 1;
      const unsigned v = (unsigned)__builtin_amdgcn_readlane((int)kt, l);
      gt = gt > v ? gt : v;
    }
    const unsigned long long gk = ((unsigned long long)gd << 32) | gt;
    if (((it + 1) >> 2) == tid) kreg[(it + 1) & 3] = gk;  // winner for m=it+1
    // winner wave's lane (unique: slots partition across waves)
    const unsigned long long wm = __ballot(((lane < 8) && (kc == gk)) ? 1 : 0);
    const int wl = (int)__builtin_ctzll(wm);
    cx = __uint_as_float((unsigned)__builtin_amdgcn_readlane(__float_as_int(cand.x), wl));
    cy = __uint_as_float((unsigned)__builtin_amdgcn_readlane(__float_as_int(cand.y), wl));
    cz = __uint_as_float((unsigned)__builtin_amdgcn_readlane(__float_as_int(cand.z), wl));
    buf ^= 1;
  }
  // coalesced writeback: thread t owns centers m = 4t..4t+3
#pragma unroll
  for (int r = 0; r < 4; ++r) {
    unsigned long long k = kreg[r];
    int orig = 8191 - (int)((k >> 13) & 0x1fff);
    int sl = (int)(k & 0x1fff);
    int m = 4 * tid + r;
    float4 c = lC4[sl];
    cidx[b * MCTR + m] = orig;
    centers[(size_t)b * 3 * MCTR + m] = c.x;
    centers[(size_t)b * 3 * MCTR + MCTR + m] = c.y;
    centers[(size_t)b * 3 * MCTR + 2 * MCTR + m] = c.z;
  }
}

// ---------- ball query: one wave per center, software-pipelined loads ----------
__global__ __launch_bounds__(256) void ballq_kernel(const float* __restrict__ coords,
                                                    const int* __restrict__ cidx,
                                                    int* __restrict__ nbidx) {
  const int wib = threadIdx.x >> 6;
  const int gw = blockIdx.x * 4 + wib;
  const int lane = threadIdx.x & 63;
  const int b = gw >> 11;
  const float* C = coords + (size_t)b * 3 * NPTS;
  const int ci = cidx[gw];
  const float cx = C[ci], cy = C[NPTS + ci], cz = C[2 * NPTS + ci];
  // python double 0.2*0.2 demoted to f32 == 0x3D23D70A (NOT 0.2f*0.2f!)
  const float R2 = (float)(0.2 * 0.2);
  __shared__ int sbuf[4][32];
  int* buf = sbuf[wib];
  int count = 0;
  float xx = C[lane], yy = C[NPTS + lane], zz = C[2 * NPTS + lane];
  for (int base = 0; base < NPTS && count < 32; base += 64) {
    float nx = 0.f, ny = 0.f, nz = 0.f;
    if (base + 64 < NPTS) {  // prefetch next round while this round resolves
      const int ni = base + 64 + lane;
      nx = C[ni]; ny = C[NPTS + ni]; nz = C[2 * NPTS + ni];
    }
    float dx = __fsub_rn(cx, xx);
    float dy = __fsub_rn(cy, yy);
    float dz = __fsub_rn(cz, zz);
    float d2 = __fadd_rn(__fadd_rn(__fmul_rn(dx, dx), __fmul_rn(dy, dy)), __fmul_rn(dz, dz));
    bool q = d2 < R2;
    unsigned long long mk = __ballot(q ? 1 : 0);
    int pos = count + (int)__popcll(mk & ((1ull << lane) - 1ull));
    if (q && pos < 32) buf[pos] = base + lane;
    count += (int)__popcll(mk);
    xx = nx; yy = ny; zz = nz;
  }
  __syncthreads();
  if (lane < 32) {
    int cnt = count < 32 ? count : 32;
    int first = (count > 0) ? buf[0] : 0;
    int v = (lane < cnt) ? buf[lane] : first;
    nbidx[(size_t)gw * KNB + lane] = v;
  }
}

// ---------- MLP with XOR-swizzled LDS ----------
__device__ __forceinline__ int SW(int ch, int col) {
  return 32 * ch + (col ^ ((((ch) >> 2) & 7) << 2));
}

__device__ __forceinline__ void layerT(const float* __restrict__ X,
                                       const float* __restrict__ W, int ldw, int cin,
                                       float4 bias, int og, int kg, float acc[4][8]) {
  const float bv[4] = {bias.x, bias.y, bias.z, bias.w};
#pragma unroll
  for (int oi = 0; oi < 4; ++oi)
#pragma unroll
    for (int ki = 0; ki < 8; ++ki) acc[oi][ki] = bv[oi];
#pragma unroll 4
  for (int c = 0; c < cin; ++c) {
    const float4 xa = *(const float4*)(X + SW(c, 8 * kg));
    const float4 xb = *(const float4*)(X + SW(c, 8 * kg + 4));
    float4 w = *(const float4*)(W + ldw * c + 4 * og);
    const float wv[4] = {w.x, w.y, w.z, w.w};
    const float xv[8] = {xa.x, xa.y, xa.z, xa.w, xb.x, xb.y, xb.z, xb.w};
#pragma unroll
    for (int oi = 0; oi < 4; ++oi)
#pragma unroll
      for (int ki = 0; ki < 8; ++ki)
        acc[oi][ki] = fmaf(wv[oi], xv[ki], acc[oi][ki]);
  }
}

__device__ __forceinline__ void storeT(float* __restrict__ dst, int og, int kg,
                                       const float acc[4][8]) {
#pragma unroll
  for (int oi = 0; oi < 4; ++oi) {
    float4 va, vb;
    va.x = fmaxf(acc[oi][0], 0.f); va.y = fmaxf(acc[oi][1], 0.f);
    va.z = fmaxf(acc[oi][2], 0.f); va.w = fmaxf(acc[oi][3], 0.f);
    vb.x = fmaxf(acc[oi][4], 0.f); vb.y = fmaxf(acc[oi][5], 0.f);
    vb.z = fmaxf(acc[oi][6], 0.f); vb.w = fmaxf(acc[oi][7], 0.f);
    const int r = 4 * og + oi;
    *(float4*)(dst + SW(r, 8 * kg)) = va;
    *(float4*)(dst + SW(r, 8 * kg + 4)) = vb;
  }
}

__global__ __launch_bounds__(64) void mlp_kernel(const float* __restrict__ coords,
                                                 const float* __restrict__ featT,
                                                 const float* __restrict__ Wt,
                                                 const float* __restrict__ b1,
                                                 const float* __restrict__ b2,
                                                 const float* __restrict__ b3,
                                                 const int* __restrict__ cidx,
                                                 const int* __restrict__ nbidx,
                                                 float* __restrict__ outT) {
  const int g = blockIdx.x;
  const int b = g >> 11;
  const int lane = threadIdx.x;
  const int og = lane & 15, kg = lane >> 4;
  __shared__ __align__(16) float A[64 * 32];
  __shared__ __align__(16) float Bf[64 * 32];
  const float* C = coords + (size_t)b * 3 * NPTS;
  const int ci = cidx[g];
  const float ccx = C[ci], ccy = C[NPTS + ci], ccz = C[2 * NPTS + ci];
  const int* nb = nbidx + (size_t)g * KNB;
  if (lane < 32) {
    const int n = nb[lane];
    A[SW(0, lane)] = C[n] - ccx;
    A[SW(1, lane)] = C[NPTS + n] - ccy;
    A[SW(2, lane)] = C[2 * NPTS + n] - ccz;
    const float4* f = (const float4*)(featT + ((size_t)b * NPTS + n) * 32);
#pragma unroll
    for (int q = 0; q < 4; ++q) {
      float4 v = f[q];
      A[SW(3 + 4 * q, lane)] = v.x;
      A[SW(4 + 4 * q, lane)] = v.y;
      A[SW(5 + 4 * q, lane)] = v.z;
      A[SW(6 + 4 * q, lane)] = v.w;
    }
  } else {
    const int k = lane - 32;
    const int n = nb[k];
    const float4* f = (const float4*)(featT + ((size_t)b * NPTS + n) * 32);
#pragma unroll
    for (int q = 4; q < 8; ++q) {
      float4 v = f[q];
      A[SW(3 + 4 * q, k)] = v.x;
      A[SW(4 + 4 * q, k)] = v.y;
      A[SW(5 + 4 * q, k)] = v.z;
      A[SW(6 + 4 * q, k)] = v.w;
    }
  }
  __syncthreads();
  float acc[4][8];
  layerT(A, Wt, 64, 35, *(const float4*)(b1 + 4 * og), og, kg, acc);
  storeT(Bf, og, kg, acc);
  __syncthreads();
  layerT(Bf, Wt + 2240, 64, 64, *(const float4*)(b2 + 4 * og), og, kg, acc);
  storeT(A, og, kg, acc);
  __syncthreads();
  float* outp = outT + (size_t)g * 128;
#pragma unroll 1
  for (int h = 0; h < 2; ++h) {
    layerT(A, Wt + 6336 + 64 * h, 128, 64, *(const float4*)(b3 + 64 * h + 4 * og), og,
           kg, acc);
    float4 res;
    float* rp = (float*)&res;
#pragma unroll
    for (int oi = 0; oi < 4; ++oi) {
      float m = 0.f;
#pragma unroll
      for (int ki = 0; ki < 8; ++ki) m = fmaxf(m, acc[oi][ki]);
      m = fmaxf(m, __shfl_xor(m, 16));
      m = fmaxf(m, __shfl_xor(m, 32));
      rp[oi] = m;
    }
    if (kg == 0) *(float4*)(outp + 64 * h + 4 * og) = res;
  }
}

// ---------- output transpose (B,M,128) -> (B,128,M) ----------
__global__ __launch_bounds__(256) void outT_kernel(const float* __restrict__ outT,
                                                   float* __restrict__ out) {
  const int bid = blockIdx.x;
  const int b = bid >> 8;
  const int r = bid & 255;
  const int o0 = (r >> 6) * 32;
  const int m0 = (r & 63) * 32;
  __shared__ float tile[32][33];
  const int tx = threadIdx.x & 31, ty = threadIdx.x >> 5;
  const float* src = outT + ((size_t)b * MCTR + m0) * 128;
#pragma unroll
  for (int s = 0; s < 4; ++s) {
    int m = ty + 8 * s;
    tile[m][tx] = src[(size_t)m * 128 + o0 + tx];
  }
  __syncthreads();
  float* dst = out + ((size_t)b * 128 + o0) * MCTR + m0;
#pragma unroll
  for (int s = 0; s < 4; ++s) {
    int o = ty + 8 * s;
    dst[(size_t)o * MCTR + tx] = tile[tx][o];
  }
}

extern "C" void kernel_launch(void* const* d_in, const int* in_sizes, int n_in,
                              void* d_out, int out_size, void* d_ws, size_t ws_size,
                              hipStream_t stream) {
  (void)in_sizes; (void)n_in; (void)out_size; (void)ws_size;
  const float* feats = (const float*)d_in[0];
  const float* coords = (const float*)d_in[1];
  const float* W1 = (const float*)d_in[2];
  const float* b1 = (const float*)d_in[3];
  const float* W2 = (const float*)d_in[4];
  const float* b2 = (const float*)d_in[5];
  const float* W3 = (const float*)d_in[6];
  const float* b3 = (const float*)d_in[7];
  float* out = (float*)d_out;
  float* centers = out + (size_t)BATCH * 128 * MCTR;

  float* ws_f = (float*)d_ws;
  float* featT = ws_f;                                     // 1,048,576 f
  float* Wt = ws_f + 1048576;                              //    14,528 f
  int* cidx = (int*)(ws_f + 1048576 + 14528);              //     8,192 i
  int* nbidx = (int*)(ws_f + 1048576 + 14528 + 8192);      //   262,144 i
  float* outTbuf = ws_f + 1048576 + 14528 + 8192 + 262144; // 1,048,576 f

  featT_kernel<<<1024, 256, 0, stream>>>(feats, featT);
  prep_kernel<<<32, 256, 0, stream>>>(W1, W2, W3, Wt);
  fps_kernel<<<BATCH, 512, 0, stream>>>(coords, cidx, centers);
  ballq_kernel<<<2048, 256, 0, stream>>>(coords, cidx, nbidx);
  mlp_kernel<<<BATCH * MCTR, 64, 0, stream>>>(coords, featT, Wt, b1, b2, b3, cidx, nbidx, outTbuf);
  outT_kernel<<<1024, 256, 0, stream>>>(outTbuf, out);
}

// Round 4
// 1573.994 us; speedup vs baseline: 1.5103x; 1.1975x over previous
//
#include <hip/hip_runtime.h>
#include <cstdint>
#include <cstddef>

#define NPTS 8192
#define MCTR 2048
#define BATCH 4
#define KNB 32

typedef float v2f __attribute__((ext_vector_type(2)));

// ---- u32 wave max via DPP (identity 0, values >= 0), foldable to v_max_u32_dpp.
// row_shr:N pushes data to HIGHER lanes; max accumulates in lane 63. ----
__device__ __forceinline__ unsigned wave_max_u32(unsigned x) {
  unsigned t;
  t = (unsigned)__builtin_amdgcn_update_dpp(0, (int)x, 0x111, 0xf, 0xf, false);
  x = x > t ? x : t;
  t = (unsigned)__builtin_amdgcn_update_dpp(0, (int)x, 0x112, 0xf, 0xf, false);
  x = x > t ? x : t;
  t = (unsigned)__builtin_amdgcn_update_dpp(0, (int)x, 0x114, 0xf, 0xf, false);
  x = x > t ? x : t;
  t = (unsigned)__builtin_amdgcn_update_dpp(0, (int)x, 0x118, 0xf, 0xf, false);
  x = x > t ? x : t;
  t = (unsigned)__builtin_amdgcn_update_dpp(0, (int)x, 0x142, 0xa, 0xf, false);
  x = x > t ? x : t;
  t = (unsigned)__builtin_amdgcn_update_dpp(0, (int)x, 0x143, 0xc, 0xf, false);
  x = x > t ? x : t;
  return (unsigned)__builtin_amdgcn_readlane((int)x, 63);
}

// ---------- fused kernel ----------
// blocks 0..3     : FPS (one per batch) — proven R0 structure (1520us) with ONE
//                   change: cross-wave reduce via ds_max_u64 atomic on a u64
//                   lexicographic key instead of skey[] + oct DPP reduce.
//                   (max dist, then min orig idx among achievers) == lexicographic
//                   max of (dist<<32 | tail): tails unique per slot, so the
//                   selection is bit-identical. 3-buffer gkey rotation makes the
//                   zero-reset race-free (zero happens one barrier after last read).
// blocks 4..515   : feature transpose (B,32,N)->(B,N,32), two 32x32 tiles/block,
//                   overlapped with FPS on idle CUs (was a serial launch).
// blocks 516..531 : weight transpose, same overlap.
__global__ __launch_bounds__(512) void fused_kernel(
    const float* __restrict__ feats, float* __restrict__ featT,
    const float* __restrict__ W1, const float* __restrict__ W2,
    const float* __restrict__ W3, float* __restrict__ Wt,
    const float* __restrict__ coords, int* __restrict__ cidx,
    float* __restrict__ centers) {
  __shared__ __align__(16) float4 lC4[NPTS];  // 128 KiB (w = orig idx bits)
  __shared__ unsigned long long gkey[3];
  __shared__ int h[512];
  __shared__ int cur[512];
  __shared__ int s_slot0;
  const int bid = blockIdx.x;
  const int tid = threadIdx.x;

  if (bid >= 516) {  // ---- weight transpose path ----
    const int t = (bid - 516) * 512 + tid;
    if (t < 2240) { int c = t >> 6, o = t & 63;  Wt[t] = W1[o * 35 + c]; }
    if (t < 4096) { int c = t >> 6, o = t & 63;  Wt[2240 + t] = W2[o * 64 + c]; }
    if (t < 8192) { int c = t >> 7, o = t & 127; Wt[6336 + t] = W3[o * 64 + c]; }
    return;
  }
  if (bid >= 4) {  // ---- feature transpose path (2 tiles per block) ----
    const int q = bid - 4;
    const int half = tid >> 8, t = tid & 255;
    const int bn = q * 2 + half;          // 0..1023
    const int b = bn >> 8;
    const int n0 = (bn & 255) * 32;
    float* tile = ((float*)lC4) + half * (32 * 33);
    const int tx = t & 31, ty = t >> 5;
    const float* src = feats + (size_t)b * 32 * NPTS;
#pragma unroll
    for (int s = 0; s < 4; ++s) {
      int f = ty + 8 * s;
      tile[f * 33 + tx] = src[(size_t)f * NPTS + n0 + tx];
    }
    __syncthreads();
    float* dst = featT + ((size_t)b * NPTS + n0) * 32;
#pragma unroll
    for (int s = 0; s < 4; ++s) {
      int n = ty + 8 * s;
      dst[n * 32 + tx] = tile[tx * 33 + n];
    }
    return;
  }

  // ---- FPS path (blocks 0..3) ----
  const int b = bid;
  const int lane = tid & 63;
  const float* C = coords + (size_t)b * 3 * NPTS;
  // --- histogram ---
  h[tid] = 0;
  __syncthreads();
  int bk[16];
#pragma unroll
  for (int j = 0; j < 16; ++j) {
    const int i = tid + j * 512;
    const float x = C[i];
    int k = (int)(x * 512.0f);
    k = k < 0 ? 0 : (k > 511 ? 511 : k);
    bk[j] = k;
    atomicAdd(&h[k], 1);
  }
  __syncthreads();
  // --- Hillis-Steele inclusive scan over h ---
  const int cnt = h[tid];
  for (int s = 1; s < 512; s <<= 1) {
    int v = (tid >= s) ? h[tid - s] : 0;
    __syncthreads();
    h[tid] += v;
    __syncthreads();
  }
  cur[tid] = h[tid] - cnt;  // exclusive start of bucket tid
  __syncthreads();
  // --- scatter into LDS (within-bucket order nondeterministic; harmless) ---
#pragma unroll
  for (int j = 0; j < 16; ++j) {
    const int i = tid + j * 512;
    const int pos = atomicAdd(&cur[bk[j]], 1);
    float4 v;
    v.x = C[i];
    v.y = C[NPTS + i];
    v.z = C[2 * NPTS + i];
    v.w = __int_as_float(i);  // ORIGINAL index, bit-stashed
    lC4[pos] = v;
  }
  if (tid < 3) gkey[tid] = 0ull;
  __syncthreads();
  // --- blocked read of owned slots ---
  const int base = tid * 16;
  int og[16];
  v2f px[8], py[8], pz[8], dd[8];
#pragma unroll
  for (int p = 0; p < 8; ++p) {
    float4 c0 = lC4[base + 2 * p];
    float4 c1 = lC4[base + 2 * p + 1];
    px[p].x = c0.x; px[p].y = c1.x;
    py[p].x = c0.y; py[p].y = c1.y;
    pz[p].x = c0.z; pz[p].y = c1.z;
    og[2 * p] = __float_as_int(c0.w);
    og[2 * p + 1] = __float_as_int(c1.w);
    dd[p].x = __builtin_inff(); dd[p].y = __builtin_inff();
  }
#pragma unroll
  for (int j = 0; j < 16; ++j)
    if (og[j] == 0) s_slot0 = base + j;  // exactly one thread writes
  // exact bbox of owned points
  v2f xl = px[0], xh = px[0], yl = py[0], yh = py[0], zl = pz[0], zh = pz[0];
#pragma unroll
  for (int p = 1; p < 8; ++p) {
    xl = __builtin_elementwise_min(xl, px[p]); xh = __builtin_elementwise_max(xh, px[p]);
    yl = __builtin_elementwise_min(yl, py[p]); yh = __builtin_elementwise_max(yh, py[p]);
    zl = __builtin_elementwise_min(zl, pz[p]); zh = __builtin_elementwise_max(zh, pz[p]);
  }
  const float xlo = fminf(xl.x, xl.y), xhi = fmaxf(xh.x, xh.y);
  const float ylo = fminf(yl.x, yl.y), yhi = fmaxf(yh.x, yh.y);
  const float zlo = fminf(zl.x, zl.y), zhi = fmaxf(zh.x, zh.y);
  __syncthreads();
  float cmax = __builtin_inff();
  int amin17 = (og[0] << 4) | 0;
#pragma unroll
  for (int j = 1; j < 16; ++j) amin17 = min(amin17, (og[j] << 4) | j);
  const int slot0 = s_slot0;
  float4 cc = lC4[slot0];
  float cx = cc.x, cy = cc.y, cz = cc.z;
  unsigned long long wkey = 0;
  unsigned long long kreg[4];
  if (tid == 0)  // m=0: initial point, orig 0 (dist bits unused by writeback)
    kreg[0] = ((unsigned long long)(unsigned)8191 << 13) | (unsigned)slot0;
  int gb = 0, gz = 2;  // atomic buffer / zero target (3-phase rotation)
  for (int it = 0; it < MCTR; ++it) {
    float dxm = fmaxf(fmaxf(xlo - cx, cx - xhi), 0.0f);
    float dym = fmaxf(fmaxf(ylo - cy, cy - yhi), 0.0f);
    float dzm = fmaxf(fmaxf(zlo - cz, cz - zhi), 0.0f);
    float lb = dxm * dxm + dym * dym + dzm * dzm;
    bool active = !(lb * 0.999999f >= cmax);  // margin makes skip provably exact
    unsigned long long mk = __ballot(active ? 1 : 0);
    if (mk != 0ull) {
      if (active) {
        v2f vcx, vcy, vcz;
        vcx.x = cx; vcx.y = cx;
        vcy.x = cy; vcy.y = cy;
        vcz.x = cz; vcz.y = cz;
        {
#pragma clang fp contract(off)
          // EXACT reference order per half: (dx*dx + dy*dy) + dz*dz, rn each
          // step, no FMA (contract off). Packed == scalar bit-exact.
#pragma unroll
          for (int p = 0; p < 8; ++p) {
            v2f dx = px[p] - vcx;
            v2f dy = py[p] - vcy;
            v2f dz = pz[p] - vcz;
            v2f d = (dx * dx + dy * dy) + dz * dz;
            dd[p] = __builtin_elementwise_min(dd[p], d);
          }
        }
        v2f m01 = __builtin_elementwise_max(dd[0], dd[1]);
        v2f m23 = __builtin_elementwise_max(dd[2], dd[3]);
        v2f m45 = __builtin_elementwise_max(dd[4], dd[5]);
        v2f m67 = __builtin_elementwise_max(dd[6], dd[7]);
        v2f m03 = __builtin_elementwise_max(m01, m23);
        v2f m47 = __builtin_elementwise_max(m45, m67);
        v2f mm = __builtin_elementwise_max(m03, m47);
        cmax = fmaxf(mm.x, mm.y);
        // min ORIGINAL idx among achievers — depth-4 tree
        int c0, c1, c2, c3, c4, c5, c6, c7;
        c0 = min(dd[0].x == cmax ? ((og[0] << 4) | 0) : 0x7fffffff,
                 dd[0].y == cmax ? ((og[1] << 4) | 1) : 0x7fffffff);
        c1 = min(dd[1].x == cmax ? ((og[2] << 4) | 2) : 0x7fffffff,
                 dd[1].y == cmax ? ((og[3] << 4) | 3) : 0x7fffffff);
        c2 = min(dd[2].x == cmax ? ((og[4] << 4) | 4) : 0x7fffffff,
                 dd[2].y == cmax ? ((og[5] << 4) | 5) : 0x7fffffff);
        c3 = min(dd[3].x == cmax ? ((og[6] << 4) | 6) : 0x7fffffff,
                 dd[3].y == cmax ? ((og[7] << 4) | 7) : 0x7fffffff);
        c4 = min(dd[4].x == cmax ? ((og[8] << 4) | 8) : 0x7fffffff,
                 dd[4].y == cmax ? ((og[9] << 4) | 9) : 0x7fffffff);
        c5 = min(dd[5].x == cmax ? ((og[10] << 4) | 10) : 0x7fffffff,
                 dd[5].y == cmax ? ((og[11] << 4) | 11) : 0x7fffffff);
        c6 = min(dd[6].x == cmax ? ((og[12] << 4) | 12) : 0x7fffffff,
                 dd[6].y == cmax ? ((og[13] << 4) | 13) : 0x7fffffff);
        c7 = min(dd[7].x == cmax ? ((og[14] << 4) | 14) : 0x7fffffff,
                 dd[7].y == cmax ? ((og[15] << 4) | 15) : 0x7fffffff);
        amin17 = min(min(min(c0, c1), min(c2, c3)), min(min(c4, c5), min(c6, c7)));
      }
      const unsigned mydist = __float_as_uint(cmax);
      const unsigned mytail =
          ((unsigned)(8191 - (amin17 >> 4)) << 13) | (unsigned)(base + (amin17 & 15));
      const unsigned gwd = wave_max_u32(mydist);                       // phase A
      const unsigned gwt = wave_max_u32(mydist == gwd ? mytail : 0u);  // phase B
      wkey = ((unsigned long long)gwd << 32) | gwt;
    }
    // cross-wave reduce: ONE non-returning ds_max_u64 per wave. Lexicographic
    // u64 max == (max dist, then max tail == min orig idx). Fire-and-forget,
    // uncontended under skewed arrival.
    if (lane == 0) atomicMax(&gkey[gb], wkey);
    __syncthreads();
    const unsigned long long gk = gkey[gb];   // broadcast b64 read
    if (tid == 0) gkey[gz] = 0ull;            // reset: read again 2 barriers out
    if (((it + 1) >> 2) == tid) kreg[(it + 1) & 3] = gk;  // winner for m=it+1
    const int slot = (int)((unsigned)gk & 0x1fffu);
    float4 c2 = lC4[slot];  // ONE ds_read_b128, wave-uniform broadcast
    cx = c2.x; cy = c2.y; cz = c2.z;
    gb = gb == 2 ? 0 : gb + 1;
    gz = gz == 2 ? 0 : gz + 1;
  }
  // coalesced writeback: thread t owns centers m = 4t..4t+3
#pragma unroll
  for (int r = 0; r < 4; ++r) {
    unsigned long long k = kreg[r];
    int orig = 8191 - (int)((k >> 13) & 0x1fff);
    int sl = (int)(k & 0x1fff);
    int m = 4 * tid + r;
    float4 c = lC4[sl];
    cidx[b * MCTR + m] = orig;
    centers[(size_t)b * 3 * MCTR + m] = c.x;
    centers[(size_t)b * 3 * MCTR + MCTR + m] = c.y;
    centers[(size_t)b * 3 * MCTR + 2 * MCTR + m] = c.z;
  }
}

// ---------- ball query: one wave per center, software-pipelined loads ----------
__global__ __launch_bounds__(256) void ballq_kernel(const float* __restrict__ coords,
                                                    const int* __restrict__ cidx,
                                                    int* __restrict__ nbidx) {
  const int wib = threadIdx.x >> 6;
  const int gw = blockIdx.x * 4 + wib;
  const int lane = threadIdx.x & 63;
  const int b = gw >> 11;
  const float* C = coords + (size_t)b * 3 * NPTS;
  const int ci = cidx[gw];
  const float cx = C[ci], cy = C[NPTS + ci], cz = C[2 * NPTS + ci];
  // python double 0.2*0.2 demoted to f32 == 0x3D23D70A (NOT 0.2f*0.2f!)
  const float R2 = (float)(0.2 * 0.2);
  __shared__ int sbuf[4][32];
  int* buf = sbuf[wib];
  int count = 0;
  float xx = C[lane], yy = C[NPTS + lane], zz = C[2 * NPTS + lane];
  for (int base = 0; base < NPTS && count < 32; base += 64) {
    float nx = 0.f, ny = 0.f, nz = 0.f;
    if (base + 64 < NPTS) {  // prefetch next round while this round resolves
      const int ni = base + 64 + lane;
      nx = C[ni]; ny = C[NPTS + ni]; nz = C[2 * NPTS + ni];
    }
    float dx = __fsub_rn(cx, xx);
    float dy = __fsub_rn(cy, yy);
    float dz = __fsub_rn(cz, zz);
    float d2 = __fadd_rn(__fadd_rn(__fmul_rn(dx, dx), __fmul_rn(dy, dy)), __fmul_rn(dz, dz));
    bool q = d2 < R2;
    unsigned long long mk = __ballot(q ? 1 : 0);
    int pos = count + (int)__popcll(mk & ((1ull << lane) - 1ull));
    if (q && pos < 32) buf[pos] = base + lane;
    count += (int)__popcll(mk);
    xx = nx; yy = ny; zz = nz;
  }
  __syncthreads();
  if (lane < 32) {
    int cnt = count < 32 ? count : 32;
    int first = (count > 0) ? buf[0] : 0;
    int v = (lane < cnt) ? buf[lane] : first;
    nbidx[(size_t)gw * KNB + lane] = v;
  }
}

// ---------- MLP with XOR-swizzled LDS ----------
__device__ __forceinline__ int SW(int ch, int col) {
  return 32 * ch + (col ^ ((((ch) >> 2) & 7) << 2));
}

__device__ __forceinline__ void layerT(const float* __restrict__ X,
                                       const float* __restrict__ W, int ldw, int cin,
                                       float4 bias, int og, int kg, float acc[4][8]) {
  const float bv[4] = {bias.x, bias.y, bias.z, bias.w};
#pragma unroll
  for (int oi = 0; oi < 4; ++oi)
#pragma unroll
    for (int ki = 0; ki < 8; ++ki) acc[oi][ki] = bv[oi];
#pragma unroll 4
  for (int c = 0; c < cin; ++c) {
    const float4 xa = *(const float4*)(X + SW(c, 8 * kg));
    const float4 xb = *(const float4*)(X + SW(c, 8 * kg + 4));
    float4 w = *(const float4*)(W + ldw * c + 4 * og);
    const float wv[4] = {w.x, w.y, w.z, w.w};
    const float xv[8] = {xa.x, xa.y, xa.z, xa.w, xb.x, xb.y, xb.z, xb.w};
#pragma unroll
    for (int oi = 0; oi < 4; ++oi)
#pragma unroll
      for (int ki = 0; ki < 8; ++ki)
        acc[oi][ki] = fmaf(wv[oi], xv[ki], acc[oi][ki]);
  }
}

__device__ __forceinline__ void storeT(float* __restrict__ dst, int og, int kg,
                                       const float acc[4][8]) {
#pragma unroll
  for (int oi = 0; oi < 4; ++oi) {
    float4 va, vb;
    va.x = fmaxf(acc[oi][0], 0.f); va.y = fmaxf(acc[oi][1], 0.f);
    va.z = fmaxf(acc[oi][2], 0.f); va.w = fmaxf(acc[oi][3], 0.f);
    vb.x = fmaxf(acc[oi][4], 0.f); vb.y = fmaxf(acc[oi][5], 0.f);
    vb.z = fmaxf(acc[oi][6], 0.f); vb.w = fmaxf(acc[oi][7], 0.f);
    const int r = 4 * og + oi;
    *(float4*)(dst + SW(r, 8 * kg)) = va;
    *(float4*)(dst + SW(r, 8 * kg + 4)) = vb;
  }
}

__global__ __launch_bounds__(64) void mlp_kernel(const float* __restrict__ coords,
                                                 const float* __restrict__ featT,
                                                 const float* __restrict__ Wt,
                                                 const float* __restrict__ b1,
                                                 const float* __restrict__ b2,
                                                 const float* __restrict__ b3,
                                                 const int* __restrict__ cidx,
                                                 const int* __restrict__ nbidx,
                                                 float* __restrict__ outT) {
  const int g = blockIdx.x;
  const int b = g >> 11;
  const int lane = threadIdx.x;
  const int og = lane & 15, kg = lane >> 4;
  __shared__ __align__(16) float A[64 * 32];
  __shared__ __align__(16) float Bf[64 * 32];
  const float* C = coords + (size_t)b * 3 * NPTS;
  const int ci = cidx[g];
  const float ccx = C[ci], ccy = C[NPTS + ci], ccz = C[2 * NPTS + ci];
  const int* nb = nbidx + (size_t)g * KNB;
  if (lane < 32) {
    const int n = nb[lane];
    A[SW(0, lane)] = C[n] - ccx;
    A[SW(1, lane)] = C[NPTS + n] - ccy;
    A[SW(2, lane)] = C[2 * NPTS + n] - ccz;
    const float4* f = (const float4*)(featT + ((size_t)b * NPTS + n) * 32);
#pragma unroll
    for (int q = 0; q < 4; ++q) {
      float4 v = f[q];
      A[SW(3 + 4 * q, lane)] = v.x;
      A[SW(4 + 4 * q, lane)] = v.y;
      A[SW(5 + 4 * q, lane)] = v.z;
      A[SW(6 + 4 * q, lane)] = v.w;
    }
  } else {
    const int k = lane - 32;
    const int n = nb[k];
    const float4* f = (const float4*)(featT + ((size_t)b * NPTS + n) * 32);
#pragma unroll
    for (int q = 4; q < 8; ++q) {
      float4 v = f[q];
      A[SW(3 + 4 * q, k)] = v.x;
      A[SW(4 + 4 * q, k)] = v.y;
      A[SW(5 + 4 * q, k)] = v.z;
      A[SW(6 + 4 * q, k)] = v.w;
    }
  }
  __syncthreads();
  float acc[4][8];
  layerT(A, Wt, 64, 35, *(const float4*)(b1 + 4 * og), og, kg, acc);
  storeT(Bf, og, kg, acc);
  __syncthreads();
  layerT(Bf, Wt + 2240, 64, 64, *(const float4*)(b2 + 4 * og), og, kg, acc);
  storeT(A, og, kg, acc);
  __syncthreads();
  float* outp = outT + (size_t)g * 128;
#pragma unroll 1
  for (int h = 0; h < 2; ++h) {
    layerT(A, Wt + 6336 + 64 * h, 128, 64, *(const float4*)(b3 + 64 * h + 4 * og), og,
           kg, acc);
    float4 res;
    float* rp = (float*)&res;
#pragma unroll
    for (int oi = 0; oi < 4; ++oi) {
      float m = 0.f;
#pragma unroll
      for (int ki = 0; ki < 8; ++ki) m = fmaxf(m, acc[oi][ki]);
      m = fmaxf(m, __shfl_xor(m, 16));
      m = fmaxf(m, __shfl_xor(m, 32));
      rp[oi] = m;
    }
    if (kg == 0) *(float4*)(outp + 64 * h + 4 * og) = res;
  }
}

// ---------- output transpose (B,M,128) -> (B,128,M) ----------
__global__ __launch_bounds__(256) void outT_kernel(const float* __restrict__ outT,
                                                   float* __restrict__ out) {
  const int bid = blockIdx.x;
  const int b = bid >> 8;
  const int r = bid & 255;
  const int o0 = (r >> 6) * 32;
  const int m0 = (r & 63) * 32;
  __shared__ float tile[32][33];
  const int tx = threadIdx.x & 31, ty = threadIdx.x >> 5;
  const float* src = outT + ((size_t)b * MCTR + m0) * 128;
#pragma unroll
  for (int s = 0; s < 4; ++s) {
    int m = ty + 8 * s;
    tile[m][tx] = src[(size_t)m * 128 + o0 + tx];
  }
  __syncthreads();
  float* dst = out + ((size_t)b * 128 + o0) * MCTR + m0;
#pragma unroll
  for (int s = 0; s < 4; ++s) {
    int o = ty + 8 * s;
    dst[(size_t)o * MCTR + tx] = tile[tx][o];
  }
}

extern "C" void kernel_launch(void* const* d_in, const int* in_sizes, int n_in,
                              void* d_out, int out_size, void* d_ws, size_t ws_size,
                              hipStream_t stream) {
  (void)in_sizes; (void)n_in; (void)out_size; (void)ws_size;
  const float* feats = (const float*)d_in[0];
  const float* coords = (const float*)d_in[1];
  const float* W1 = (const float*)d_in[2];
  const float* b1 = (const float*)d_in[3];
  const float* W2 = (const float*)d_in[4];
  const float* b2 = (const float*)d_in[5];
  const float* W3 = (const float*)d_in[6];
  const float* b3 = (const float*)d_in[7];
  float* out = (float*)d_out;
  float* centers = out + (size_t)BATCH * 128 * MCTR;

  float* ws_f = (float*)d_ws;
  float* featT = ws_f;                                     // 1,048,576 f
  float* Wt = ws_f + 1048576;                              //    14,528 f
  int* cidx = (int*)(ws_f + 1048576 + 14528);              //     8,192 i
  int* nbidx = (int*)(ws_f + 1048576 + 14528 + 8192);      //   262,144 i
  float* outTbuf = ws_f + 1048576 + 14528 + 8192 + 262144; // 1,048,576 f

  // blocks: 0..3 fps | 4..515 featT | 516..531 prep — transposes overlap fps
  fused_kernel<<<532, 512, 0, stream>>>(feats, featT, W1, W2, W3, Wt, coords, cidx,
                                        centers);
  ballq_kernel<<<2048, 256, 0, stream>>>(coords, cidx, nbidx);
  mlp_kernel<<<BATCH * MCTR, 64, 0, stream>>>(coords, featT, Wt, b1, b2, b3, cidx, nbidx, outTbuf);
  outT_kernel<<<1024, 256, 0, stream>>>(outTbuf, out);
}

// Round 5
// 1460.831 us; speedup vs baseline: 1.6273x; 1.0775x over previous
//
#include <hip/hip_runtime.h>
#include <cstdint>
#include <cstddef>

#define NPTS 8192
#define MCTR 2048
#define BATCH 4
#define KNB 32

typedef float v2f __attribute__((ext_vector_type(2)));

// ---- u32 wave max via DPP (identity 0, values >= 0), foldable to v_max_u32_dpp.
// row_shr:N pushes data to HIGHER lanes; max accumulates in lane 63. ----
__device__ __forceinline__ unsigned wave_max_u32(unsigned x) {
  unsigned t;
  t = (unsigned)__builtin_amdgcn_update_dpp(0, (int)x, 0x111, 0xf, 0xf, false);
  x = x > t ? x : t;
  t = (unsigned)__builtin_amdgcn_update_dpp(0, (int)x, 0x112, 0xf, 0xf, false);
  x = x > t ? x : t;
  t = (unsigned)__builtin_amdgcn_update_dpp(0, (int)x, 0x114, 0xf, 0xf, false);
  x = x > t ? x : t;
  t = (unsigned)__builtin_amdgcn_update_dpp(0, (int)x, 0x118, 0xf, 0xf, false);
  x = x > t ? x : t;
  t = (unsigned)__builtin_amdgcn_update_dpp(0, (int)x, 0x142, 0xa, 0xf, false);
  x = x > t ? x : t;
  t = (unsigned)__builtin_amdgcn_update_dpp(0, (int)x, 0x143, 0xc, 0xf, false);
  x = x > t ? x : t;
  return (unsigned)__builtin_amdgcn_readlane((int)x, 63);
}

// ---------- fused kernel (1024 threads/block) ----------
// blocks 0..3     : FPS (one per batch). R4 structure with two changes:
//                   (1) 1024 threads x 8 owned points (halves the active-wave
//                       update that sets barrier-release time; active x-slab
//                       spreads across SIMDs so halved updates run parallel);
//                   (2) achiever-fires-atomic: after phase-A wave max (gwd),
//                       lanes with mydist==gwd fire ds_max_u64 with the full
//                       lexicographic key (dist<<32|tail) directly — phase-B
//                       DPP chain and the active/inactive wkey caching branch
//                       are deleted. max over fired keys == max over all
//                       lanes' (dist,tail) == R4's two-phase result, bit-exact.
// blocks 4..259   : feature transpose (B,32,N)->(B,N,32), 4 tiles per block.
// blocks 260..267 : weight transpose.
__global__ __launch_bounds__(1024) void fused_kernel(
    const float* __restrict__ feats, float* __restrict__ featT,
    const float* __restrict__ W1, const float* __restrict__ W2,
    const float* __restrict__ W3, float* __restrict__ Wt,
    const float* __restrict__ coords, int* __restrict__ cidx,
    float* __restrict__ centers) {
  __shared__ __align__(16) float4 lC4[NPTS];  // 128 KiB (w = orig idx bits)
  __shared__ unsigned long long gkey[3];
  __shared__ int h[512];
  __shared__ int cur[512];
  __shared__ int s_slot0;
  const int bid = blockIdx.x;
  const int tid = threadIdx.x;

  if (bid >= 260) {  // ---- weight transpose path ----
    const int t = (bid - 260) * 1024 + tid;
    if (t < 2240) { int c = t >> 6, o = t & 63;  Wt[t] = W1[o * 35 + c]; }
    if (t < 4096) { int c = t >> 6, o = t & 63;  Wt[2240 + t] = W2[o * 64 + c]; }
    if (t < 8192) { int c = t >> 7, o = t & 127; Wt[6336 + t] = W3[o * 64 + c]; }
    return;
  }
  if (bid >= 4) {  // ---- feature transpose path (4 tiles per block) ----
    const int q = bid - 4;             // 0..255
    const int quarter = tid >> 8, t = tid & 255;
    const int bn = q * 4 + quarter;    // 0..1023
    const int b = bn >> 8;
    const int n0 = (bn & 255) * 32;
    float* tile = ((float*)lC4) + quarter * (32 * 33);
    const int tx = t & 31, ty = t >> 5;
    const float* src = feats + (size_t)b * 32 * NPTS;
#pragma unroll
    for (int s = 0; s < 4; ++s) {
      int f = ty + 8 * s;
      tile[f * 33 + tx] = src[(size_t)f * NPTS + n0 + tx];
    }
    __syncthreads();
    float* dst = featT + ((size_t)b * NPTS + n0) * 32;
#pragma unroll
    for (int s = 0; s < 4; ++s) {
      int n = ty + 8 * s;
      dst[n * 32 + tx] = tile[tx * 33 + n];
    }
    return;
  }

  // ---- FPS path (blocks 0..3) ----
  const int b = bid;
  const float* C = coords + (size_t)b * 3 * NPTS;
  // --- histogram (512 x-buckets, 8 points/thread) ---
  if (tid < 512) h[tid] = 0;
  __syncthreads();
  int bk[8];
#pragma unroll
  for (int j = 0; j < 8; ++j) {
    const int i = tid + j * 1024;
    const float x = C[i];
    int k = (int)(x * 512.0f);
    k = k < 0 ? 0 : (k > 511 ? 511 : k);
    bk[j] = k;
    atomicAdd(&h[k], 1);
  }
  __syncthreads();
  // --- Hillis-Steele inclusive scan over h (tid<512 participate) ---
  const int cnt = (tid < 512) ? h[tid] : 0;
  for (int s = 1; s < 512; s <<= 1) {
    int v = (tid >= s && tid < 512) ? h[tid - s] : 0;
    __syncthreads();
    if (tid < 512) h[tid] += v;
    __syncthreads();
  }
  if (tid < 512) cur[tid] = h[tid] - cnt;  // exclusive start of bucket tid
  __syncthreads();
  // --- scatter into LDS (within-bucket order nondeterministic; harmless) ---
#pragma unroll
  for (int j = 0; j < 8; ++j) {
    const int i = tid + j * 1024;
    const int pos = atomicAdd(&cur[bk[j]], 1);
    float4 v;
    v.x = C[i];
    v.y = C[NPTS + i];
    v.z = C[2 * NPTS + i];
    v.w = __int_as_float(i);  // ORIGINAL index, bit-stashed
    lC4[pos] = v;
  }
  if (tid < 3) gkey[tid] = 0ull;
  __syncthreads();
  // --- blocked read of owned slots (8 per thread) ---
  const int base = tid * 8;
  int og[8];
  v2f px[4], py[4], pz[4], dd[4];
#pragma unroll
  for (int p = 0; p < 4; ++p) {
    float4 c0 = lC4[base + 2 * p];
    float4 c1 = lC4[base + 2 * p + 1];
    px[p].x = c0.x; px[p].y = c1.x;
    py[p].x = c0.y; py[p].y = c1.y;
    pz[p].x = c0.z; pz[p].y = c1.z;
    og[2 * p] = __float_as_int(c0.w);
    og[2 * p + 1] = __float_as_int(c1.w);
    dd[p].x = __builtin_inff(); dd[p].y = __builtin_inff();
  }
#pragma unroll
  for (int j = 0; j < 8; ++j)
    if (og[j] == 0) s_slot0 = base + j;  // exactly one thread writes
  // exact bbox of owned points
  v2f xl = px[0], xh = px[0], yl = py[0], yh = py[0], zl = pz[0], zh = pz[0];
#pragma unroll
  for (int p = 1; p < 4; ++p) {
    xl = __builtin_elementwise_min(xl, px[p]); xh = __builtin_elementwise_max(xh, px[p]);
    yl = __builtin_elementwise_min(yl, py[p]); yh = __builtin_elementwise_max(yh, py[p]);
    zl = __builtin_elementwise_min(zl, pz[p]); zh = __builtin_elementwise_max(zh, pz[p]);
  }
  const float xlo = fminf(xl.x, xl.y), xhi = fmaxf(xh.x, xh.y);
  const float ylo = fminf(yl.x, yl.y), yhi = fmaxf(yh.x, yh.y);
  const float zlo = fminf(zl.x, zl.y), zhi = fmaxf(zh.x, zh.y);
  __syncthreads();
  float cmax = __builtin_inff();
  int amin = (og[0] << 3) | 0;
#pragma unroll
  for (int j = 1; j < 8; ++j) amin = min(amin, (og[j] << 3) | j);
  const int slot0 = s_slot0;
  float4 cc = lC4[slot0];
  float cx = cc.x, cy = cc.y, cz = cc.z;
  unsigned long long kreg[2];
  if (tid == 0)  // m=0: initial point, orig 0 (dist bits unused by writeback)
    kreg[0] = ((unsigned long long)(unsigned)8191 << 13) | (unsigned)slot0;
  int gb = 0, gz = 2;  // atomic buffer / zero target (3-phase rotation)
  for (int it = 0; it < MCTR; ++it) {
    float dxm = fmaxf(fmaxf(xlo - cx, cx - xhi), 0.0f);
    float dym = fmaxf(fmaxf(ylo - cy, cy - yhi), 0.0f);
    float dzm = fmaxf(fmaxf(zlo - cz, cz - zhi), 0.0f);
    float lb = dxm * dxm + dym * dym + dzm * dzm;
    bool active = !(lb * 0.999999f >= cmax);  // margin makes skip provably exact
    if (active) {
      v2f vcx, vcy, vcz;
      vcx.x = cx; vcx.y = cx;
      vcy.x = cy; vcy.y = cy;
      vcz.x = cz; vcz.y = cz;
      {
#pragma clang fp contract(off)
        // EXACT reference order per half: (dx*dx + dy*dy) + dz*dz, rn each
        // step, no FMA (contract off). Packed == scalar bit-exact.
#pragma unroll
        for (int p = 0; p < 4; ++p) {
          v2f dx = px[p] - vcx;
          v2f dy = py[p] - vcy;
          v2f dz = pz[p] - vcz;
          v2f d = (dx * dx + dy * dy) + dz * dz;
          dd[p] = __builtin_elementwise_min(dd[p], d);
        }
      }
      v2f m01 = __builtin_elementwise_max(dd[0], dd[1]);
      v2f m23 = __builtin_elementwise_max(dd[2], dd[3]);
      v2f mm = __builtin_elementwise_max(m01, m23);
      cmax = fmaxf(mm.x, mm.y);
      // min ORIGINAL idx among achievers — depth-3 tree
      const int I = 0x7fffffff;
      int c0 = min(dd[0].x == cmax ? ((og[0] << 3) | 0) : I,
                   dd[0].y == cmax ? ((og[1] << 3) | 1) : I);
      int c1 = min(dd[1].x == cmax ? ((og[2] << 3) | 2) : I,
                   dd[1].y == cmax ? ((og[3] << 3) | 3) : I);
      int c2 = min(dd[2].x == cmax ? ((og[4] << 3) | 4) : I,
                   dd[2].y == cmax ? ((og[5] << 3) | 5) : I);
      int c3 = min(dd[3].x == cmax ? ((og[6] << 3) | 6) : I,
                   dd[3].y == cmax ? ((og[7] << 3) | 7) : I);
      amin = min(min(c0, c1), min(c2, c3));
    }
    // ---- uniform reduce: phase-A wave max, then achiever lanes fire the
    // full lexicographic u64 key. Stale (inactive) lanes fire stale-but-valid
    // contributions == R4's cached-wkey re-fire. Bit-identical selection. ----
    const unsigned mydist = __float_as_uint(cmax);
    const unsigned mytail =
        ((unsigned)(8191 - (amin >> 3)) << 13) | (unsigned)(base + (amin & 7));
    const unsigned gwd = wave_max_u32(mydist);
    if (mydist == gwd)
      atomicMax(&gkey[gb], ((unsigned long long)mydist << 32) | mytail);
    __syncthreads();
    const unsigned long long gk = gkey[gb];   // broadcast b64 read
    if (tid == 0) gkey[gz] = 0ull;            // reset: read again 2 barriers out
    if (((it + 1) >> 1) == tid) kreg[(it + 1) & 1] = gk;  // winner for m=it+1
    const int slot = (int)((unsigned)gk & 0x1fffu);
    float4 c2 = lC4[slot];  // ONE ds_read_b128, wave-uniform broadcast
    cx = c2.x; cy = c2.y; cz = c2.z;
    gb = gb == 2 ? 0 : gb + 1;
    gz = gz == 2 ? 0 : gz + 1;
  }
  // coalesced writeback: thread t owns centers m = 2t..2t+1
#pragma unroll
  for (int r = 0; r < 2; ++r) {
    unsigned long long k = kreg[r];
    int orig = 8191 - (int)((k >> 13) & 0x1fff);
    int sl = (int)(k & 0x1fff);
    int m = 2 * tid + r;
    float4 c = lC4[sl];
    cidx[b * MCTR + m] = orig;
    centers[(size_t)b * 3 * MCTR + m] = c.x;
    centers[(size_t)b * 3 * MCTR + MCTR + m] = c.y;
    centers[(size_t)b * 3 * MCTR + 2 * MCTR + m] = c.z;
  }
}

// ---------- ball query: one wave per center, software-pipelined loads ----------
__global__ __launch_bounds__(256) void ballq_kernel(const float* __restrict__ coords,
                                                    const int* __restrict__ cidx,
                                                    int* __restrict__ nbidx) {
  const int wib = threadIdx.x >> 6;
  const int gw = blockIdx.x * 4 + wib;
  const int lane = threadIdx.x & 63;
  const int b = gw >> 11;
  const float* C = coords + (size_t)b * 3 * NPTS;
  const int ci = cidx[gw];
  const float cx = C[ci], cy = C[NPTS + ci], cz = C[2 * NPTS + ci];
  // python double 0.2*0.2 demoted to f32 == 0x3D23D70A (NOT 0.2f*0.2f!)
  const float R2 = (float)(0.2 * 0.2);
  __shared__ int sbuf[4][32];
  int* buf = sbuf[wib];
  int count = 0;
  float xx = C[lane], yy = C[NPTS + lane], zz = C[2 * NPTS + lane];
  for (int base = 0; base < NPTS && count < 32; base += 64) {
    float nx = 0.f, ny = 0.f, nz = 0.f;
    if (base + 64 < NPTS) {  // prefetch next round while this round resolves
      const int ni = base + 64 + lane;
      nx = C[ni]; ny = C[NPTS + ni]; nz = C[2 * NPTS + ni];
    }
    float dx = __fsub_rn(cx, xx);
    float dy = __fsub_rn(cy, yy);
    float dz = __fsub_rn(cz, zz);
    float d2 = __fadd_rn(__fadd_rn(__fmul_rn(dx, dx), __fmul_rn(dy, dy)), __fmul_rn(dz, dz));
    bool q = d2 < R2;
    unsigned long long mk = __ballot(q ? 1 : 0);
    int pos = count + (int)__popcll(mk & ((1ull << lane) - 1ull));
    if (q && pos < 32) buf[pos] = base + lane;
    count += (int)__popcll(mk);
    xx = nx; yy = ny; zz = nz;
  }
  __syncthreads();
  if (lane < 32) {
    int cnt = count < 32 ? count : 32;
    int first = (count > 0) ? buf[0] : 0;
    int v = (lane < cnt) ? buf[lane] : first;
    nbidx[(size_t)gw * KNB + lane] = v;
  }
}

// ---------- MLP with XOR-swizzled LDS ----------
__device__ __forceinline__ int SW(int ch, int col) {
  return 32 * ch + (col ^ ((((ch) >> 2) & 7) << 2));
}

__device__ __forceinline__ void layerT(const float* __restrict__ X,
                                       const float* __restrict__ W, int ldw, int cin,
                                       float4 bias, int og, int kg, float acc[4][8]) {
  const float bv[4] = {bias.x, bias.y, bias.z, bias.w};
#pragma unroll
  for (int oi = 0; oi < 4; ++oi)
#pragma unroll
    for (int ki = 0; ki < 8; ++ki) acc[oi][ki] = bv[oi];
#pragma unroll 4
  for (int c = 0; c < cin; ++c) {
    const float4 xa = *(const float4*)(X + SW(c, 8 * kg));
    const float4 xb = *(const float4*)(X + SW(c, 8 * kg + 4));
    float4 w = *(const float4*)(W + ldw * c + 4 * og);
    const float wv[4] = {w.x, w.y, w.z, w.w};
    const float xv[8] = {xa.x, xa.y, xa.z, xa.w, xb.x, xb.y, xb.z, xb.w};
#pragma unroll
    for (int oi = 0; oi < 4; ++oi)
#pragma unroll
      for (int ki = 0; ki < 8; ++ki)
        acc[oi][ki] = fmaf(wv[oi], xv[ki], acc[oi][ki]);
  }
}

__device__ __forceinline__ void storeT(float* __restrict__ dst, int og, int kg,
                                       const float acc[4][8]) {
#pragma unroll
  for (int oi = 0; oi < 4; ++oi) {
    float4 va, vb;
    va.x = fmaxf(acc[oi][0], 0.f); va.y = fmaxf(acc[oi][1], 0.f);
    va.z = fmaxf(acc[oi][2], 0.f); va.w = fmaxf(acc[oi][3], 0.f);
    vb.x = fmaxf(acc[oi][4], 0.f); vb.y = fmaxf(acc[oi][5], 0.f);
    vb.z = fmaxf(acc[oi][6], 0.f); vb.w = fmaxf(acc[oi][7], 0.f);
    const int r = 4 * og + oi;
    *(float4*)(dst + SW(r, 8 * kg)) = va;
    *(float4*)(dst + SW(r, 8 * kg + 4)) = vb;
  }
}

__global__ __launch_bounds__(64) void mlp_kernel(const float* __restrict__ coords,
                                                 const float* __restrict__ featT,
                                                 const float* __restrict__ Wt,
                                                 const float* __restrict__ b1,
                                                 const float* __restrict__ b2,
                                                 const float* __restrict__ b3,
                                                 const int* __restrict__ cidx,
                                                 const int* __restrict__ nbidx,
                                                 float* __restrict__ outT) {
  const int g = blockIdx.x;
  const int b = g >> 11;
  const int lane = threadIdx.x;
  const int og = lane & 15, kg = lane >> 4;
  __shared__ __align__(16) float A[64 * 32];
  __shared__ __align__(16) float Bf[64 * 32];
  const float* C = coords + (size_t)b * 3 * NPTS;
  const int ci = cidx[g];
  const float ccx = C[ci], ccy = C[NPTS + ci], ccz = C[2 * NPTS + ci];
  const int* nb = nbidx + (size_t)g * KNB;
  if (lane < 32) {
    const int n = nb[lane];
    A[SW(0, lane)] = C[n] - ccx;
    A[SW(1, lane)] = C[NPTS + n] - ccy;
    A[SW(2, lane)] = C[2 * NPTS + n] - ccz;
    const float4* f = (const float4*)(featT + ((size_t)b * NPTS + n) * 32);
#pragma unroll
    for (int q = 0; q < 4; ++q) {
      float4 v = f[q];
      A[SW(3 + 4 * q, lane)] = v.x;
      A[SW(4 + 4 * q, lane)] = v.y;
      A[SW(5 + 4 * q, lane)] = v.z;
      A[SW(6 + 4 * q, lane)] = v.w;
    }
  } else {
    const int k = lane - 32;
    const int n = nb[k];
    const float4* f = (const float4*)(featT + ((size_t)b * NPTS + n) * 32);
#pragma unroll
    for (int q = 4; q < 8; ++q) {
      float4 v = f[q];
      A[SW(3 + 4 * q, k)] = v.x;
      A[SW(4 + 4 * q, k)] = v.y;
      A[SW(5 + 4 * q, k)] = v.z;
      A[SW(6 + 4 * q, k)] = v.w;
    }
  }
  __syncthreads();
  float acc[4][8];
  layerT(A, Wt, 64, 35, *(const float4*)(b1 + 4 * og), og, kg, acc);
  storeT(Bf, og, kg, acc);
  __syncthreads();
  layerT(Bf, Wt + 2240, 64, 64, *(const float4*)(b2 + 4 * og), og, kg, acc);
  storeT(A, og, kg, acc);
  __syncthreads();
  float* outp = outT + (size_t)g * 128;
#pragma unroll 1
  for (int h = 0; h < 2; ++h) {
    layerT(A, Wt + 6336 + 64 * h, 128, 64, *(const float4*)(b3 + 64 * h + 4 * og), og,
           kg, acc);
    float4 res;
    float* rp = (float*)&res;
#pragma unroll
    for (int oi = 0; oi < 4; ++oi) {
      float m = 0.f;
#pragma unroll
      for (int ki = 0; ki < 8; ++ki) m = fmaxf(m, acc[oi][ki]);
      m = fmaxf(m, __shfl_xor(m, 16));
      m = fmaxf(m, __shfl_xor(m, 32));
      rp[oi] = m;
    }
    if (kg == 0) *(float4*)(outp + 64 * h + 4 * og) = res;
  }
}

// ---------- output transpose (B,M,128) -> (B,128,M) ----------
__global__ __launch_bounds__(256) void outT_kernel(const float* __restrict__ outT,
                                                   float* __restrict__ out) {
  const int bid = blockIdx.x;
  const int b = bid >> 8;
  const int r = bid & 255;
  const int o0 = (r >> 6) * 32;
  const int m0 = (r & 63) * 32;
  __shared__ float tile[32][33];
  const int tx = threadIdx.x & 31, ty = threadIdx.x >> 5;
  const float* src = outT + ((size_t)b * MCTR + m0) * 128;
#pragma unroll
  for (int s = 0; s < 4; ++s) {
    int m = ty + 8 * s;
    tile[m][tx] = src[(size_t)m * 128 + o0 + tx];
  }
  __syncthreads();
  float* dst = out + ((size_t)b * 128 + o0) * MCTR + m0;
#pragma unroll
  for (int s = 0; s < 4; ++s) {
    int o = ty + 8 * s;
    dst[(size_t)o * MCTR + tx] = tile[tx][o];
  }
}

extern "C" void kernel_launch(void* const* d_in, const int* in_sizes, int n_in,
                              void* d_out, int out_size, void* d_ws, size_t ws_size,
                              hipStream_t stream) {
  (void)in_sizes; (void)n_in; (void)out_size; (void)ws_size;
  const float* feats = (const float*)d_in[0];
  const float* coords = (const float*)d_in[1];
  const float* W1 = (const float*)d_in[2];
  const float* b1 = (const float*)d_in[3];
  const float* W2 = (const float*)d_in[4];
  const float* b2 = (const float*)d_in[5];
  const float* W3 = (const float*)d_in[6];
  const float* b3 = (const float*)d_in[7];
  float* out = (float*)d_out;
  float* centers = out + (size_t)BATCH * 128 * MCTR;

  float* ws_f = (float*)d_ws;
  float* featT = ws_f;                                     // 1,048,576 f
  float* Wt = ws_f + 1048576;                              //    14,528 f
  int* cidx = (int*)(ws_f + 1048576 + 14528);              //     8,192 i
  int* nbidx = (int*)(ws_f + 1048576 + 14528 + 8192);      //   262,144 i
  float* outTbuf = ws_f + 1048576 + 14528 + 8192 + 262144; // 1,048,576 f

  // blocks: 0..3 fps | 4..259 featT | 260..267 prep — transposes overlap fps
  fused_kernel<<<268, 1024, 0, stream>>>(feats, featT, W1, W2, W3, Wt, coords, cidx,
                                         centers);
  ballq_kernel<<<2048, 256, 0, stream>>>(coords, cidx, nbidx);
  mlp_kernel<<<BATCH * MCTR, 64, 0, stream>>>(coords, featT, Wt, b1, b2, b3, cidx, nbidx, outTbuf);
  outT_kernel<<<1024, 256, 0, stream>>>(outTbuf, out);
}

// Round 6
// 1364.499 us; speedup vs baseline: 1.7422x; 1.0706x over previous
//
#include <hip/hip_runtime.h>
#include <cstdint>
#include <cstddef>

#define NPTS 8192
#define MCTR 2048
#define BATCH 4
#define KNB 32

typedef float v2f __attribute__((ext_vector_type(2)));

// ---- u32 wave max via DPP (identity 0, values >= 0), foldable to v_max_u32_dpp.
// row_shr:N pushes data to HIGHER lanes; max accumulates in lane 63. ----
__device__ __forceinline__ unsigned wave_max_u32(unsigned x) {
  unsigned t;
  t = (unsigned)__builtin_amdgcn_update_dpp(0, (int)x, 0x111, 0xf, 0xf, false);
  x = x > t ? x : t;
  t = (unsigned)__builtin_amdgcn_update_dpp(0, (int)x, 0x112, 0xf, 0xf, false);
  x = x > t ? x : t;
  t = (unsigned)__builtin_amdgcn_update_dpp(0, (int)x, 0x114, 0xf, 0xf, false);
  x = x > t ? x : t;
  t = (unsigned)__builtin_amdgcn_update_dpp(0, (int)x, 0x118, 0xf, 0xf, false);
  x = x > t ? x : t;
  t = (unsigned)__builtin_amdgcn_update_dpp(0, (int)x, 0x142, 0xa, 0xf, false);
  x = x > t ? x : t;
  t = (unsigned)__builtin_amdgcn_update_dpp(0, (int)x, 0x143, 0xc, 0xf, false);
  x = x > t ? x : t;
  return (unsigned)__builtin_amdgcn_readlane((int)x, 63);
}

// ---------- fused kernel (1024 threads/block) ----------
// blocks 0..3     : FPS (one per batch). R5 structure + cached-fire wave skip:
//                   per-lane persistent (mydist, mytail, mykey) recomputed only
//                   when the lane is active; per-lane persistent fire flag
//                   recomputed only when the WAVE has >=1 active lane (gwd
//                   cannot change otherwise). Fully-culled waves skip the DPP
//                   chain + key assembly and re-fire cached achiever keys —
//                   value-identical to a full recompute (their lanes' cmax/amin
//                   are unchanged), so the atomicMax sees the same key multiset
//                   => bit-identical selection. Winning wave is always active
//                   next iteration (winner's owner has lb=0), so staleness is
//                   never wrong. Inactive waves fire early => atomic drain
//                   overlaps active waves' update.
// blocks 4..259   : feature transpose (B,32,N)->(B,N,32), 4 tiles per block.
// blocks 260..267 : weight transpose.
__global__ __launch_bounds__(1024) void fused_kernel(
    const float* __restrict__ feats, float* __restrict__ featT,
    const float* __restrict__ W1, const float* __restrict__ W2,
    const float* __restrict__ W3, float* __restrict__ Wt,
    const float* __restrict__ coords, int* __restrict__ cidx,
    float* __restrict__ centers) {
  __shared__ __align__(16) float4 lC4[NPTS];  // 128 KiB (w = orig idx bits)
  __shared__ unsigned long long gkey[3];
  __shared__ int h[512];
  __shared__ int cur[512];
  __shared__ int s_slot0;
  const int bid = blockIdx.x;
  const int tid = threadIdx.x;

  if (bid >= 260) {  // ---- weight transpose path ----
    const int t = (bid - 260) * 1024 + tid;
    if (t < 2240) { int c = t >> 6, o = t & 63;  Wt[t] = W1[o * 35 + c]; }
    if (t < 4096) { int c = t >> 6, o = t & 63;  Wt[2240 + t] = W2[o * 64 + c]; }
    if (t < 8192) { int c = t >> 7, o = t & 127; Wt[6336 + t] = W3[o * 64 + c]; }
    return;
  }
  if (bid >= 4) {  // ---- feature transpose path (4 tiles per block) ----
    const int q = bid - 4;             // 0..255
    const int quarter = tid >> 8, t = tid & 255;
    const int bn = q * 4 + quarter;    // 0..1023
    const int b = bn >> 8;
    const int n0 = (bn & 255) * 32;
    float* tile = ((float*)lC4) + quarter * (32 * 33);
    const int tx = t & 31, ty = t >> 5;
    const float* src = feats + (size_t)b * 32 * NPTS;
#pragma unroll
    for (int s = 0; s < 4; ++s) {
      int f = ty + 8 * s;
      tile[f * 33 + tx] = src[(size_t)f * NPTS + n0 + tx];
    }
    __syncthreads();
    float* dst = featT + ((size_t)b * NPTS + n0) * 32;
#pragma unroll
    for (int s = 0; s < 4; ++s) {
      int n = ty + 8 * s;
      dst[n * 32 + tx] = tile[tx * 33 + n];
    }
    return;
  }

  // ---- FPS path (blocks 0..3) ----
  const int b = bid;
  const float* C = coords + (size_t)b * 3 * NPTS;
  // --- histogram (512 x-buckets, 8 points/thread) ---
  if (tid < 512) h[tid] = 0;
  __syncthreads();
  int bk[8];
#pragma unroll
  for (int j = 0; j < 8; ++j) {
    const int i = tid + j * 1024;
    const float x = C[i];
    int k = (int)(x * 512.0f);
    k = k < 0 ? 0 : (k > 511 ? 511 : k);
    bk[j] = k;
    atomicAdd(&h[k], 1);
  }
  __syncthreads();
  // --- Hillis-Steele inclusive scan over h (tid<512 participate) ---
  const int cnt = (tid < 512) ? h[tid] : 0;
  for (int s = 1; s < 512; s <<= 1) {
    int v = (tid >= s && tid < 512) ? h[tid - s] : 0;
    __syncthreads();
    if (tid < 512) h[tid] += v;
    __syncthreads();
  }
  if (tid < 512) cur[tid] = h[tid] - cnt;  // exclusive start of bucket tid
  __syncthreads();
  // --- scatter into LDS (within-bucket order nondeterministic; harmless) ---
#pragma unroll
  for (int j = 0; j < 8; ++j) {
    const int i = tid + j * 1024;
    const int pos = atomicAdd(&cur[bk[j]], 1);
    float4 v;
    v.x = C[i];
    v.y = C[NPTS + i];
    v.z = C[2 * NPTS + i];
    v.w = __int_as_float(i);  // ORIGINAL index, bit-stashed
    lC4[pos] = v;
  }
  if (tid < 3) gkey[tid] = 0ull;
  __syncthreads();
  // --- blocked read of owned slots (8 per thread) ---
  const int base = tid * 8;
  int og[8];
  v2f px[4], py[4], pz[4], dd[4];
#pragma unroll
  for (int p = 0; p < 4; ++p) {
    float4 c0 = lC4[base + 2 * p];
    float4 c1 = lC4[base + 2 * p + 1];
    px[p].x = c0.x; px[p].y = c1.x;
    py[p].x = c0.y; py[p].y = c1.y;
    pz[p].x = c0.z; pz[p].y = c1.z;
    og[2 * p] = __float_as_int(c0.w);
    og[2 * p + 1] = __float_as_int(c1.w);
    dd[p].x = __builtin_inff(); dd[p].y = __builtin_inff();
  }
#pragma unroll
  for (int j = 0; j < 8; ++j)
    if (og[j] == 0) s_slot0 = base + j;  // exactly one thread writes
  // exact bbox of owned points
  v2f xl = px[0], xh = px[0], yl = py[0], yh = py[0], zl = pz[0], zh = pz[0];
#pragma unroll
  for (int p = 1; p < 4; ++p) {
    xl = __builtin_elementwise_min(xl, px[p]); xh = __builtin_elementwise_max(xh, px[p]);
    yl = __builtin_elementwise_min(yl, py[p]); yh = __builtin_elementwise_max(yh, py[p]);
    zl = __builtin_elementwise_min(zl, pz[p]); zh = __builtin_elementwise_max(zh, pz[p]);
  }
  const float xlo = fminf(xl.x, xl.y), xhi = fmaxf(xh.x, xh.y);
  const float ylo = fminf(yl.x, yl.y), yhi = fmaxf(yh.x, yh.y);
  const float zlo = fminf(zl.x, zl.y), zhi = fmaxf(zh.x, zh.y);
  __syncthreads();
  float cmax = __builtin_inff();
  int amin = (og[0] << 3) | 0;
#pragma unroll
  for (int j = 1; j < 8; ++j) amin = min(amin, (og[j] << 3) | j);
  const int slot0 = s_slot0;
  float4 cc = lC4[slot0];
  float cx = cc.x, cy = cc.y, cz = cc.z;
  unsigned long long kreg[2];
  if (tid == 0)  // m=0: initial point, orig 0 (dist bits unused by writeback)
    kreg[0] = ((unsigned long long)(unsigned)8191 << 13) | (unsigned)slot0;
  // cached-fire state (all initialized on it=0: every lane active then)
  unsigned mydist = 0, mytail = 0;
  unsigned long long mykey = 0ull;
  bool fire = false;
  int gb = 0, gz = 2;  // atomic buffer / zero target (3-phase rotation)
  for (int it = 0; it < MCTR; ++it) {
    float dxm = fmaxf(fmaxf(xlo - cx, cx - xhi), 0.0f);
    float dym = fmaxf(fmaxf(ylo - cy, cy - yhi), 0.0f);
    float dzm = fmaxf(fmaxf(zlo - cz, cz - zhi), 0.0f);
    float lb = dxm * dxm + dym * dym + dzm * dzm;
    bool active = !(lb * 0.999999f >= cmax);  // margin makes skip provably exact
    const unsigned long long mk = __ballot(active ? 1 : 0);
    if (mk != 0ull) {  // wave has work: refresh update + DPP reduce + fire set
      if (active) {
        v2f vcx, vcy, vcz;
        vcx.x = cx; vcx.y = cx;
        vcy.x = cy; vcy.y = cy;
        vcz.x = cz; vcz.y = cz;
        {
#pragma clang fp contract(off)
          // EXACT reference order per half: (dx*dx + dy*dy) + dz*dz, rn each
          // step, no FMA (contract off). Packed == scalar bit-exact.
#pragma unroll
          for (int p = 0; p < 4; ++p) {
            v2f dx = px[p] - vcx;
            v2f dy = py[p] - vcy;
            v2f dz = pz[p] - vcz;
            v2f d = (dx * dx + dy * dy) + dz * dz;
            dd[p] = __builtin_elementwise_min(dd[p], d);
          }
        }
        v2f m01 = __builtin_elementwise_max(dd[0], dd[1]);
        v2f m23 = __builtin_elementwise_max(dd[2], dd[3]);
        v2f mm = __builtin_elementwise_max(m01, m23);
        cmax = fmaxf(mm.x, mm.y);
        // min ORIGINAL idx among achievers — depth-3 tree
        const int I = 0x7fffffff;
        int c0 = min(dd[0].x == cmax ? ((og[0] << 3) | 0) : I,
                     dd[0].y == cmax ? ((og[1] << 3) | 1) : I);
        int c1 = min(dd[1].x == cmax ? ((og[2] << 3) | 2) : I,
                     dd[1].y == cmax ? ((og[3] << 3) | 3) : I);
        int c2 = min(dd[2].x == cmax ? ((og[4] << 3) | 4) : I,
                     dd[2].y == cmax ? ((og[5] << 3) | 5) : I);
        int c3 = min(dd[3].x == cmax ? ((og[6] << 3) | 6) : I,
                     dd[3].y == cmax ? ((og[7] << 3) | 7) : I);
        amin = min(min(c0, c1), min(c2, c3));
        mydist = __float_as_uint(cmax);
        mytail = ((unsigned)(8191 - (amin >> 3)) << 13) |
                 (unsigned)(base + (amin & 7));
        mykey = ((unsigned long long)mydist << 32) | mytail;
      }
      const unsigned gwd = wave_max_u32(mydist);
      fire = (mydist == gwd);
    }
    // achiever lanes (fresh or cached) fire the lexicographic u64 key.
    // Inactive waves reach this early => their atomic drains under others' work.
    if (fire) atomicMax(&gkey[gb], mykey);
    __syncthreads();
    const unsigned long long gk = gkey[gb];   // broadcast b64 read
    if (tid == 0) gkey[gz] = 0ull;            // reset: read again 2 barriers out
    if (((it + 1) >> 1) == tid) kreg[(it + 1) & 1] = gk;  // winner for m=it+1
    const int slot = (int)((unsigned)gk & 0x1fffu);
    float4 c2 = lC4[slot];  // ONE ds_read_b128, wave-uniform broadcast
    cx = c2.x; cy = c2.y; cz = c2.z;
    gb = gb == 2 ? 0 : gb + 1;
    gz = gz == 2 ? 0 : gz + 1;
  }
  // coalesced writeback: thread t owns centers m = 2t..2t+1
#pragma unroll
  for (int r = 0; r < 2; ++r) {
    unsigned long long k = kreg[r];
    int orig = 8191 - (int)((k >> 13) & 0x1fff);
    int sl = (int)(k & 0x1fff);
    int m = 2 * tid + r;
    float4 c = lC4[sl];
    cidx[b * MCTR + m] = orig;
    centers[(size_t)b * 3 * MCTR + m] = c.x;
    centers[(size_t)b * 3 * MCTR + MCTR + m] = c.y;
    centers[(size_t)b * 3 * MCTR + 2 * MCTR + m] = c.z;
  }
}

// ---------- ball query: one wave per center, software-pipelined loads ----------
__global__ __launch_bounds__(256) void ballq_kernel(const float* __restrict__ coords,
                                                    const int* __restrict__ cidx,
                                                    int* __restrict__ nbidx) {
  const int wib = threadIdx.x >> 6;
  const int gw = blockIdx.x * 4 + wib;
  const int lane = threadIdx.x & 63;
  const int b = gw >> 11;
  const float* C = coords + (size_t)b * 3 * NPTS;
  const int ci = cidx[gw];
  const float cx = C[ci], cy = C[NPTS + ci], cz = C[2 * NPTS + ci];
  // python double 0.2*0.2 demoted to f32 == 0x3D23D70A (NOT 0.2f*0.2f!)
  const float R2 = (float)(0.2 * 0.2);
  __shared__ int sbuf[4][32];
  int* buf = sbuf[wib];
  int count = 0;
  float xx = C[lane], yy = C[NPTS + lane], zz = C[2 * NPTS + lane];
  for (int base = 0; base < NPTS && count < 32; base += 64) {
    float nx = 0.f, ny = 0.f, nz = 0.f;
    if (base + 64 < NPTS) {  // prefetch next round while this round resolves
      const int ni = base + 64 + lane;
      nx = C[ni]; ny = C[NPTS + ni]; nz = C[2 * NPTS + ni];
    }
    float dx = __fsub_rn(cx, xx);
    float dy = __fsub_rn(cy, yy);
    float dz = __fsub_rn(cz, zz);
    float d2 = __fadd_rn(__fadd_rn(__fmul_rn(dx, dx), __fmul_rn(dy, dy)), __fmul_rn(dz, dz));
    bool q = d2 < R2;
    unsigned long long mk = __ballot(q ? 1 : 0);
    int pos = count + (int)__popcll(mk & ((1ull << lane) - 1ull));
    if (q && pos < 32) buf[pos] = base + lane;
    count += (int)__popcll(mk);
    xx = nx; yy = ny; zz = nz;
  }
  __syncthreads();
  if (lane < 32) {
    int cnt = count < 32 ? count : 32;
    int first = (count > 0) ? buf[0] : 0;
    int v = (lane < cnt) ? buf[lane] : first;
    nbidx[(size_t)gw * KNB + lane] = v;
  }
}

// ---------- MLP with XOR-swizzled LDS ----------
__device__ __forceinline__ int SW(int ch, int col) {
  return 32 * ch + (col ^ ((((ch) >> 2) & 7) << 2));
}

__device__ __forceinline__ void layerT(const float* __restrict__ X,
                                       const float* __restrict__ W, int ldw, int cin,
                                       float4 bias, int og, int kg, float acc[4][8]) {
  const float bv[4] = {bias.x, bias.y, bias.z, bias.w};
#pragma unroll
  for (int oi = 0; oi < 4; ++oi)
#pragma unroll
    for (int ki = 0; ki < 8; ++ki) acc[oi][ki] = bv[oi];
#pragma unroll 4
  for (int c = 0; c < cin; ++c) {
    const float4 xa = *(const float4*)(X + SW(c, 8 * kg));
    const float4 xb = *(const float4*)(X + SW(c, 8 * kg + 4));
    float4 w = *(const float4*)(W + ldw * c + 4 * og);
    const float wv[4] = {w.x, w.y, w.z, w.w};
    const float xv[8] = {xa.x, xa.y, xa.z, xa.w, xb.x, xb.y, xb.z, xb.w};
#pragma unroll
    for (int oi = 0; oi < 4; ++oi)
#pragma unroll
      for (int ki = 0; ki < 8; ++ki)
        acc[oi][ki] = fmaf(wv[oi], xv[ki], acc[oi][ki]);
  }
}

__device__ __forceinline__ void storeT(float* __restrict__ dst, int og, int kg,
                                       const float acc[4][8]) {
#pragma unroll
  for (int oi = 0; oi < 4; ++oi) {
    float4 va, vb;
    va.x = fmaxf(acc[oi][0], 0.f); va.y = fmaxf(acc[oi][1], 0.f);
    va.z = fmaxf(acc[oi][2], 0.f); va.w = fmaxf(acc[oi][3], 0.f);
    vb.x = fmaxf(acc[oi][4], 0.f); vb.y = fmaxf(acc[oi][5], 0.f);
    vb.z = fmaxf(acc[oi][6], 0.f); vb.w = fmaxf(acc[oi][7], 0.f);
    const int r = 4 * og + oi;
    *(float4*)(dst + SW(r, 8 * kg)) = va;
    *(float4*)(dst + SW(r, 8 * kg + 4)) = vb;
  }
}

__global__ __launch_bounds__(64) void mlp_kernel(const float* __restrict__ coords,
                                                 const float* __restrict__ featT,
                                                 const float* __restrict__ Wt,
                                                 const float* __restrict__ b1,
                                                 const float* __restrict__ b2,
                                                 const float* __restrict__ b3,
                                                 const int* __restrict__ cidx,
                                                 const int* __restrict__ nbidx,
                                                 float* __restrict__ outT) {
  const int g = blockIdx.x;
  const int b = g >> 11;
  const int lane = threadIdx.x;
  const int og = lane & 15, kg = lane >> 4;
  __shared__ __align__(16) float A[64 * 32];
  __shared__ __align__(16) float Bf[64 * 32];
  const float* C = coords + (size_t)b * 3 * NPTS;
  const int ci = cidx[g];
  const float ccx = C[ci], ccy = C[NPTS + ci], ccz = C[2 * NPTS + ci];
  const int* nb = nbidx + (size_t)g * KNB;
  if (lane < 32) {
    const int n = nb[lane];
    A[SW(0, lane)] = C[n] - ccx;
    A[SW(1, lane)] = C[NPTS + n] - ccy;
    A[SW(2, lane)] = C[2 * NPTS + n] - ccz;
    const float4* f = (const float4*)(featT + ((size_t)b * NPTS + n) * 32);
#pragma unroll
    for (int q = 0; q < 4; ++q) {
      float4 v = f[q];
      A[SW(3 + 4 * q, lane)] = v.x;
      A[SW(4 + 4 * q, lane)] = v.y;
      A[SW(5 + 4 * q, lane)] = v.z;
      A[SW(6 + 4 * q, lane)] = v.w;
    }
  } else {
    const int k = lane - 32;
    const int n = nb[k];
    const float4* f = (const float4*)(featT + ((size_t)b * NPTS + n) * 32);
#pragma unroll
    for (int q = 4; q < 8; ++q) {
      float4 v = f[q];
      A[SW(3 + 4 * q, k)] = v.x;
      A[SW(4 + 4 * q, k)] = v.y;
      A[SW(5 + 4 * q, k)] = v.z;
      A[SW(6 + 4 * q, k)] = v.w;
    }
  }
  __syncthreads();
  float acc[4][8];
  layerT(A, Wt, 64, 35, *(const float4*)(b1 + 4 * og), og, kg, acc);
  storeT(Bf, og, kg, acc);
  __syncthreads();
  layerT(Bf, Wt + 2240, 64, 64, *(const float4*)(b2 + 4 * og), og, kg, acc);
  storeT(A, og, kg, acc);
  __syncthreads();
  float* outp = outT + (size_t)g * 128;
#pragma unroll 1
  for (int h = 0; h < 2; ++h) {
    layerT(A, Wt + 6336 + 64 * h, 128, 64, *(const float4*)(b3 + 64 * h + 4 * og), og,
           kg, acc);
    float4 res;
    float* rp = (float*)&res;
#pragma unroll
    for (int oi = 0; oi < 4; ++oi) {
      float m = 0.f;
#pragma unroll
      for (int ki = 0; ki < 8; ++ki) m = fmaxf(m, acc[oi][ki]);
      m = fmaxf(m, __shfl_xor(m, 16));
      m = fmaxf(m, __shfl_xor(m, 32));
      rp[oi] = m;
    }
    if (kg == 0) *(float4*)(outp + 64 * h + 4 * og) = res;
  }
}

// ---------- output transpose (B,M,128) -> (B,128,M) ----------
__global__ __launch_bounds__(256) void outT_kernel(const float* __restrict__ outT,
                                                   float* __restrict__ out) {
  const int bid = blockIdx.x;
  const int b = bid >> 8;
  const int r = bid & 255;
  const int o0 = (r >> 6) * 32;
  const int m0 = (r & 63) * 32;
  __shared__ float tile[32][33];
  const int tx = threadIdx.x & 31, ty = threadIdx.x >> 5;
  const float* src = outT + ((size_t)b * MCTR + m0) * 128;
#pragma unroll
  for (int s = 0; s < 4; ++s) {
    int m = ty + 8 * s;
    tile[m][tx] = src[(size_t)m * 128 + o0 + tx];
  }
  __syncthreads();
  float* dst = out + ((size_t)b * 128 + o0) * MCTR + m0;
#pragma unroll
  for (int s = 0; s < 4; ++s) {
    int o = ty + 8 * s;
    dst[(size_t)o * MCTR + tx] = tile[tx][o];
  }
}

extern "C" void kernel_launch(void* const* d_in, const int* in_sizes, int n_in,
                              void* d_out, int out_size, void* d_ws, size_t ws_size,
                              hipStream_t stream) {
  (void)in_sizes; (void)n_in; (void)out_size; (void)ws_size;
  const float* feats = (const float*)d_in[0];
  const float* coords = (const float*)d_in[1];
  const float* W1 = (const float*)d_in[2];
  const float* b1 = (const float*)d_in[3];
  const float* W2 = (const float*)d_in[4];
  const float* b2 = (const float*)d_in[5];
  const float* W3 = (const float*)d_in[6];
  const float* b3 = (const float*)d_in[7];
  float* out = (float*)d_out;
  float* centers = out + (size_t)BATCH * 128 * MCTR;

  float* ws_f = (float*)d_ws;
  float* featT = ws_f;                                     // 1,048,576 f
  float* Wt = ws_f + 1048576;                              //    14,528 f
  int* cidx = (int*)(ws_f + 1048576 + 14528);              //     8,192 i
  int* nbidx = (int*)(ws_f + 1048576 + 14528 + 8192);      //   262,144 i
  float* outTbuf = ws_f + 1048576 + 14528 + 8192 + 262144; // 1,048,576 f

  // blocks: 0..3 fps | 4..259 featT | 260..267 prep — transposes overlap fps
  fused_kernel<<<268, 1024, 0, stream>>>(feats, featT, W1, W2, W3, Wt, coords, cidx,
                                         centers);
  ballq_kernel<<<2048, 256, 0, stream>>>(coords, cidx, nbidx);
  mlp_kernel<<<BATCH * MCTR, 64, 0, stream>>>(coords, featT, Wt, b1, b2, b3, cidx, nbidx, outTbuf);
  outT_kernel<<<1024, 256, 0, stream>>>(outTbuf, out);
}